// Round 7
// baseline (96.178 us; speedup 1.0000x reference)
//
#include <hip/hip_runtime.h>
#include <math.h>

#define TWO_PI 6.28318530717958647692f
#define NT     1024          // 16 waves per block
#define RPW    4             // rows/cols per wave (64 / 16 waves)
#define PITCH  65            // LDS pitch (odd -> conflict-free both ways)
#define THRESH 10.0f
// unit-root recurrence constants (step = one k1 increment)
#define C4096  0.999998823451701879f
#define S4096  0.001533980186284766f

typedef float v2f __attribute__((ext_vector_type(2)));

__device__ __forceinline__ int brev6(int x) {
    return (int)(__brev((unsigned)x) >> 26);
}

// acc + a*b (complex)
__device__ __forceinline__ v2f cmul_add(v2f a, v2f b, v2f acc) {
    acc += (v2f){a.x, a.x} * b;
    acc += (v2f){a.y, a.y} * (v2f){-b.y, b.x};
    return acc;
}

// Cross-lane 64-pt DIF FFT (radix-2). Natural-order input across lanes;
// output: lane l holds coefficient brev6(l). sign=-1 fwd, +1 inverse(unnorm).
template<int R>
__device__ __forceinline__ void fft64_dif(float (&re)[R], float (&im)[R],
                                          int lane, float sign) {
    #pragma unroll
    for (int h = 32; h >= 1; h >>= 1) {
        int j = lane & (h - 1);
        float ang = sign * (TWO_PI / 64.0f) * (float)(j * (32 / h));
        float wr, wi;
        __sincosf(ang, &wi, &wr);
        bool upper = (lane & h) != 0;
        float cwr = upper ? wr : 1.0f;
        float cwi = upper ? wi : 0.0f;
        float sgn = upper ? -1.0f : 1.0f;
        #pragma unroll
        for (int m = 0; m < R; ++m) {
            float orr = __shfl_xor(re[m], h, 64);
            float oii = __shfl_xor(im[m], h, 64);
            float ar = fmaf(sgn, re[m], orr);
            float ai = fmaf(sgn, im[m], oii);
            re[m] = ar * cwr - ai * cwi;
            im[m] = ar * cwi + ai * cwr;
        }
    }
}

// Cross-lane 64-pt DIT FFT. Input bit-reversed across lanes; natural output.
template<int R>
__device__ __forceinline__ void fft64_dit(float (&re)[R], float (&im)[R],
                                          int lane, float sign) {
    #pragma unroll
    for (int h = 1; h <= 32; h <<= 1) {
        int j = lane & (h - 1);
        float ang = sign * (TWO_PI / 64.0f) * (float)(j * (32 / h));
        float wr, wi;
        __sincosf(ang, &wi, &wr);
        bool upper = (lane & h) != 0;
        float cwr = upper ? wr : 1.0f;
        float cwi = upper ? wi : 0.0f;
        float sgn = upper ? -1.0f : 1.0f;
        #pragma unroll
        for (int m = 0; m < R; ++m) {
            float tr = re[m] * cwr - im[m] * cwi;
            float ti = re[m] * cwi + im[m] * cwr;
            float orr = __shfl_xor(tr, h, 64);
            float oii = __shfl_xor(ti, h, 64);
            re[m] = fmaf(sgn, tr, orr);
            im[m] = fmaf(sgn, ti, oii);
        }
    }
}

// fwd: 128 blocks, one per (t,c). Pad 62x62 -> 64x64 in LDS, four-step
// FFT4096, threshold, store X[task][k1][l] = spectrum[k1 + 64*brev6(l)].
__global__ __launch_bounds__(NT) void fwd_kernel(const float* __restrict__ x,
                                                 float2* __restrict__ X) {
    __shared__ float sre[64 * PITCH];
    __shared__ float sim[64 * PITCH];
    const int task = blockIdx.x;
    const int tid  = threadIdx.x;
    const int lane = tid & 63;
    const int w    = tid >> 6;          // 0..15
    const float* xr = x + (size_t)task * 62 * 62;

    for (int idx = tid; idx < 4096; idx += NT) {
        int r = idx >> 6, s = idx & 63;
        float v = 0.0f;
        if (r >= 1 && r <= 62 && s >= 1 && s <= 62)
            v = xr[(r - 1) * 62 + (s - 1)];
        sre[r * PITCH + s] = v;
    }
    __syncthreads();

    float re[RPW], im[RPW];
    // Phase A: FFT over n1 (lane = n1), columns n2 = w*4 + m.
    #pragma unroll
    for (int m = 0; m < RPW; ++m) {
        re[m] = sre[lane * PITCH + (w * RPW + m)];
        im[m] = 0.0f;
    }
    fft64_dif<RPW>(re, im, lane, -1.0f);
    const int k1 = brev6(lane);
    // Mid twiddle: * e^{-2pi i k1 n2 / 4096}
    #pragma unroll
    for (int m = 0; m < RPW; ++m) {
        int n2 = w * RPW + m;
        float cr, ci;
        __sincosf(-(TWO_PI / 4096.0f) * (float)(k1 * n2), &ci, &cr);
        float rr = re[m] * cr - im[m] * ci;
        im[m]    = re[m] * ci + im[m] * cr;
        re[m]    = rr;
    }
    __syncthreads();                 // all phase-A reads done before overwrite
    #pragma unroll
    for (int m = 0; m < RPW; ++m) {
        int n2 = w * RPW + m;
        sre[k1 * PITCH + n2] = re[m];
        sim[k1 * PITCH + n2] = im[m];
    }
    __syncthreads();
    // Phase B: FFT over n2 (lane = n2), rows k1 = w*4 + m.
    #pragma unroll
    for (int m = 0; m < RPW; ++m) {
        int row = w * RPW + m;
        re[m] = sre[row * PITCH + lane];
        im[m] = sim[row * PITCH + lane];
    }
    fft64_dif<RPW>(re, im, lane, -1.0f);
    float2* Xrow = X + (size_t)task * 4096;
    #pragma unroll
    for (int m = 0; m < RPW; ++m) {
        int row = w * RPW + m;
        float rr = re[m], ii = im[m];
        if (fabsf(rr) < THRESH) { rr = 0.0f; ii = 0.0f; }
        Xrow[row * 64 + lane] = make_float2(rr, ii);
    }
}

// conv: per (t,o). m-outer / c-inner: Q[q] = sum_c W[o,c,q] * X[t,c,k]
// (9 packed FMAs per c), then S = Horner(Q; u,v) once per m. Inverse
// four-step FFT, crop + bias.
__global__ __launch_bounds__(NT, 4) void conv_kernel(const float2* __restrict__ X,
                                                     const float* __restrict__ W,
                                                     const float* __restrict__ b,
                                                     float* __restrict__ out) {
    __shared__ float sre[64 * PITCH];
    __shared__ float sim[64 * PITCH];
    const int t    = blockIdx.x >> 5;
    const int o    = blockIdx.x & 31;
    const int tid  = threadIdx.x;
    const int lane = tid & 63;
    const int w    = tid >> 6;          // 0..15

    const int k2 = brev6(lane);
    float elr, eli;          // e^{+2pi i k2/64}
    __sincosf((TWO_PI / 64.0f) * (float)k2, &eli, &elr);

    const float2* Xt = X + (size_t)t * 16 * 4096 + lane;
    const float*  wo = W + o * 144;     // block-uniform -> scalar loads

    float re[RPW], im[RPW];
    #pragma unroll
    for (int m = 0; m < RPW; ++m) {
        const int k1 = w * RPW + m;     // true k = k1 + 64*k2
        // Tap accumulation: Q[q] = sum_c W[c,q] * X[c,k]
        v2f Q0 = {0,0}, Q1 = {0,0}, Q2 = {0,0}, Q3 = {0,0}, Q4 = {0,0};
        v2f Q5 = {0,0}, Q6 = {0,0}, Q7 = {0,0}, Q8 = {0,0};
        const float2* xp = Xt + k1 * 64;
        v2f xb;
        { float2 q = xp[0]; xb = (v2f){q.x, q.y}; }
        #pragma unroll 1
        for (int c = 0; c < 16; ++c) {
            v2f xn;
            if (c < 15) { float2 q = xp[(c + 1) * 4096]; xn = (v2f){q.x, q.y}; }
            const float* wc = wo + c * 9;
            Q0 += xb * wc[0]; Q1 += xb * wc[1]; Q2 += xb * wc[2];
            Q3 += xb * wc[3]; Q4 += xb * wc[4]; Q5 += xb * wc[5];
            Q6 += xb * wc[6]; Q7 += xb * wc[7]; Q8 += xb * wc[8];
            xb = xn;
        }
        // Twiddles: u = e^{2pi i k1/64}, v = e^{2pi i k/4096} = vk1 * el
        float ur, ui, vkr, vki;
        __sincosf((TWO_PI / 64.0f) * (float)k1, &ui, &ur);
        __sincosf((TWO_PI / 4096.0f) * (float)k1, &vki, &vkr);
        v2f u  = {ur, ui};
        v2f v  = {vkr * elr - vki * eli, vkr * eli + vki * elr};
        v2f v2 = {v.x * v.x - v.y * v.y, 2.0f * v.x * v.y};
        // h_i = Q_{i0} + v*Q_{i1} + v2*Q_{i2}; S = h0 + u*(h1 + u*h2)
        v2f h0 = cmul_add(v2, Q2, cmul_add(v, Q1, Q0));
        v2f h1 = cmul_add(v2, Q5, cmul_add(v, Q4, Q3));
        v2f h2 = cmul_add(v2, Q8, cmul_add(v, Q7, Q6));
        v2f S  = cmul_add(u, cmul_add(u, h2, h1), h0);
        re[m] = S.x;
        im[m] = S.y;
    }

    // Phase 1: inverse FFT over k2 (lanes hold k2 = brev6(l) -> DIT).
    fft64_dit<RPW>(re, im, lane, +1.0f);
    // Mid twiddle: * e^{+2pi i n2 k1 / 4096}, n2 = lane, recurrence over m.
    {
        float cr, ci, sr, si;
        __sincosf((TWO_PI / 1024.0f) * (float)(lane * w), &ci, &cr);
        __sincosf((TWO_PI / 4096.0f) * (float)lane, &si, &sr);
        #pragma unroll
        for (int m = 0; m < RPW; ++m) {
            float rr = re[m] * cr - im[m] * ci;
            im[m]    = re[m] * ci + im[m] * cr;
            re[m]    = rr;
            float nr = cr * sr - ci * si;
            ci = cr * si + ci * sr; cr = nr;
        }
    }
    // Transpose through LDS: write [k1][n2].
    #pragma unroll
    for (int m = 0; m < RPW; ++m) {
        int k1 = w * RPW + m;
        sre[k1 * PITCH + lane] = re[m];
        sim[k1 * PITCH + lane] = im[m];
    }
    __syncthreads();
    // Phase 2: inverse FFT over k1 (lane = k1), columns n2 = w*4 + m.
    #pragma unroll
    for (int m = 0; m < RPW; ++m) {
        int n2 = w * RPW + m;
        re[m] = sre[lane * PITCH + n2];
        im[m] = sim[lane * PITCH + n2];
    }
    fft64_dif<RPW>(re, im, lane, +1.0f);
    __syncthreads();   // phase-2 reads done before y overwrite
    // Lane l holds y[n1 = brev6(l)][n2]; unscramble via LDS for coalesced store.
    const int n1 = brev6(lane);
    #pragma unroll
    for (int m = 0; m < RPW; ++m) {
        int n2 = w * RPW + m;
        sre[n1 * PITCH + n2] = re[m];
    }
    __syncthreads();
    const float bias = b[o];
    float* orow = out + (size_t)blockIdx.x * 62 * 62;
    for (int idx = tid; idx < 62 * 62; idx += NT) {
        int r = idx / 62, s = idx - r * 62;
        orow[idx] = sre[r * PITCH + s] * (1.0f / 4096.0f) + bias;
    }
}

extern "C" void kernel_launch(void* const* d_in, const int* in_sizes, int n_in,
                              void* d_out, int out_size, void* d_ws, size_t ws_size,
                              hipStream_t stream) {
    const float* x = (const float*)d_in[0];   // (8,16,62,62) f32
    const float* W = (const float*)d_in[1];   // (32,16,3,3)  f32
    const float* b = (const float*)d_in[2];   // (32,)        f32
    float* out = (float*)d_out;               // (8,32,62,62) f32
    float2* X = (float2*)d_ws;                // 128*4096 complex = 4 MB

    fwd_kernel<<<dim3(128), dim3(NT), 0, stream>>>(x, X);
    conv_kernel<<<dim3(256), dim3(NT), 0, stream>>>(X, W, b, out);
}

// Round 8
// 82.870 us; speedup vs baseline: 1.1606x; 1.1606x over previous
//
#include <hip/hip_runtime.h>
#include <math.h>

#define TWO_PI 6.28318530717958647692f
#define NT     1024          // 16 waves per block
#define RPW    4             // rows/cols per wave in iFFT tail (64 / 16 waves)
#define PITCH  65            // LDS pitch (odd -> conflict-free both ways)
#define THRESH 10.0f
// e^{2pi i 32/4096} = e^{2pi i/128}
#define C128   0.998795456205172393f
#define S128   0.049067674327418015f

typedef float v2f __attribute__((ext_vector_type(2)));

__device__ __forceinline__ int brev6(int x) {
    return (int)(__brev((unsigned)x) >> 26);
}

// acc + a*b (complex)
__device__ __forceinline__ v2f cmul_add(v2f a, v2f b, v2f acc) {
    acc += (v2f){a.x, a.x} * b;
    acc += (v2f){a.y, a.y} * (v2f){-b.y, b.x};
    return acc;
}

// Cross-lane 64-pt DIF FFT (radix-2). Natural-order input across lanes;
// output: lane l holds coefficient brev6(l). sign=-1 fwd, +1 inverse(unnorm).
template<int R>
__device__ __forceinline__ void fft64_dif(float (&re)[R], float (&im)[R],
                                          int lane, float sign) {
    #pragma unroll
    for (int h = 32; h >= 1; h >>= 1) {
        int j = lane & (h - 1);
        float ang = sign * (TWO_PI / 64.0f) * (float)(j * (32 / h));
        float wr, wi;
        __sincosf(ang, &wi, &wr);
        bool upper = (lane & h) != 0;
        float cwr = upper ? wr : 1.0f;
        float cwi = upper ? wi : 0.0f;
        float sgn = upper ? -1.0f : 1.0f;
        #pragma unroll
        for (int m = 0; m < R; ++m) {
            float orr = __shfl_xor(re[m], h, 64);
            float oii = __shfl_xor(im[m], h, 64);
            float ar = fmaf(sgn, re[m], orr);
            float ai = fmaf(sgn, im[m], oii);
            re[m] = ar * cwr - ai * cwi;
            im[m] = ar * cwi + ai * cwr;
        }
    }
}

// Cross-lane 64-pt DIT FFT. Input bit-reversed across lanes; natural output.
template<int R>
__device__ __forceinline__ void fft64_dit(float (&re)[R], float (&im)[R],
                                          int lane, float sign) {
    #pragma unroll
    for (int h = 1; h <= 32; h <<= 1) {
        int j = lane & (h - 1);
        float ang = sign * (TWO_PI / 64.0f) * (float)(j * (32 / h));
        float wr, wi;
        __sincosf(ang, &wi, &wr);
        bool upper = (lane & h) != 0;
        float cwr = upper ? wr : 1.0f;
        float cwi = upper ? wi : 0.0f;
        float sgn = upper ? -1.0f : 1.0f;
        #pragma unroll
        for (int m = 0; m < R; ++m) {
            float tr = re[m] * cwr - im[m] * cwi;
            float ti = re[m] * cwi + im[m] * cwr;
            float orr = __shfl_xor(tr, h, 64);
            float oii = __shfl_xor(ti, h, 64);
            re[m] = fmaf(sgn, tr, orr);
            im[m] = fmaf(sgn, ti, oii);
        }
    }
}

// fwdA: 256 blocks, 2 per (t,c); block handles 32 columns n2. Column FFT over
// n1 + mid twiddle, LDS transpose, write Xa[task][k1][n2] for k1 <= 32 only.
__global__ __launch_bounds__(NT) void fwdA_kernel(const float* __restrict__ x,
                                                  float2* __restrict__ Xa) {
    __shared__ float sre[64 * 33];
    __shared__ float sim[64 * 33];
    const int task = blockIdx.x >> 1;
    const int h    = blockIdx.x & 1;
    const int tid  = threadIdx.x;
    const int lane = tid & 63;
    const int w    = tid >> 6;          // 0..15
    const float* xr = x + (size_t)task * 62 * 62;
    for (int idx = tid; idx < 64 * 32; idx += NT) {
        int r = idx >> 5, j = idx & 31;
        int n2 = 32 * h + j;
        float v = 0.0f;
        if (r >= 1 && r <= 62 && n2 >= 1 && n2 <= 62)
            v = xr[(r - 1) * 62 + (n2 - 1)];
        sre[r * 33 + j] = v;
    }
    __syncthreads();
    float re[2], im[2];
    #pragma unroll
    for (int m = 0; m < 2; ++m) {
        re[m] = sre[lane * 33 + (w * 2 + m)];
        im[m] = 0.0f;
    }
    fft64_dif<2>(re, im, lane, -1.0f);
    __syncthreads();                 // input reads done before overwrite
    const int k1 = brev6(lane);
    #pragma unroll
    for (int m = 0; m < 2; ++m) {
        int j  = w * 2 + m;
        int n2 = 32 * h + j;
        float cr, ci;                // e^{-2pi i k1 n2 / 4096}
        __sincosf(-(TWO_PI / 4096.0f) * (float)(k1 * n2), &ci, &cr);
        sre[k1 * 33 + j] = re[m] * cr - im[m] * ci;
        sim[k1 * 33 + j] = re[m] * ci + im[m] * cr;
    }
    __syncthreads();
    float2* Arow = Xa + (size_t)task * 4096;
    for (int idx = tid; idx < 64 * 32; idx += NT) {
        int k = idx >> 5, j = idx & 31;
        if (k <= 32)                 // Hermitian: rows 33..63 never consumed
            Arow[k * 64 + 32 * h + j] =
                make_float2(sre[k * 33 + j], sim[k * 33 + j]);
    }
}

// fwdB: 256 blocks, 2 per (t,c). Row FFT over n2 + threshold for rows <= 32
// only; store X[task][k1][l] where value = spectrum[k1 + 64*brev6(l)].
__global__ __launch_bounds__(NT) void fwdB_kernel(const float2* __restrict__ Xa,
                                                  float2* __restrict__ X) {
    const int task = blockIdx.x >> 1;
    const int h    = blockIdx.x & 1;
    const int tid  = threadIdx.x;
    const int lane = tid & 63;
    const int w    = tid >> 6;          // 0..15
    if (h == 1 && w > 0) return;        // h=1 needs only row 32 (wave 0)
    const float2* Arow = Xa + (size_t)task * 4096;
    float re[2], im[2];
    #pragma unroll
    for (int m = 0; m < 2; ++m) {
        int row = 32 * h + w * 2 + m;
        float2 xv = (row <= 32) ? Arow[row * 64 + lane] : make_float2(0.f, 0.f);
        re[m] = xv.x; im[m] = xv.y;
    }
    fft64_dif<2>(re, im, lane, -1.0f);
    float2* Xrow = X + (size_t)task * 4096;
    #pragma unroll
    for (int m = 0; m < 2; ++m) {
        int row = 32 * h + w * 2 + m;
        if (row <= 32) {
            float rr = re[m], ii = im[m];
            if (fabsf(rr) < THRESH) { rr = 0.0f; ii = 0.0f; }
            Xrow[row * 64 + lane] = make_float2(rr, ii);
        }
    }
}

// conv: per (t,o). Hermitian-halved Q: each wave computes S for rows
// k1 = 2w, 2w+1 (wave 0 also row 32); rows 33..63 reconstructed as
// conj(S[64-k1][63-k2]) via LDS. Then inverse four-step FFT, crop + bias.
__global__ __launch_bounds__(NT, 4) void conv_kernel(const float2* __restrict__ X,
                                                     const float* __restrict__ W,
                                                     const float* __restrict__ b,
                                                     float* __restrict__ out) {
    __shared__ float sre[64 * PITCH];
    __shared__ float sim[64 * PITCH];
    const int t    = blockIdx.x >> 5;
    const int o    = blockIdx.x & 31;
    const int tid  = threadIdx.x;
    const int lane = tid & 63;
    const int w    = tid >> 6;          // 0..15

    const int k2 = brev6(lane);
    float elr, eli;          // e^{+2pi i k2/64}
    __sincosf((TWO_PI / 64.0f) * (float)k2, &eli, &elr);

    // Slot twiddles: A: k1=2w, B: k1=2w+1, C: k1=32 (wave 0 only).
    // u = e^{2pi i k1/64}; v = e^{2pi i (k1 + 64 k2)/4096} = e^{2pi i k1/4096}*el
    const int rA = 2 * w, rB = 2 * w + 1;
    float uAr, uAi, vAr, vAi, uBr, uBi, vBr, vBi;
    __sincosf((TWO_PI / 64.0f) * (float)rA, &uAi, &uAr);
    __sincosf((TWO_PI / 4096.0f) * (float)rA, &vAi, &vAr);
    __sincosf((TWO_PI / 64.0f) * (float)rB, &uBi, &uBr);
    __sincosf((TWO_PI / 4096.0f) * (float)rB, &vBi, &vBr);
    v2f uA = {uAr, uAi};
    v2f vA = {vAr * elr - vAi * eli, vAr * eli + vAi * elr};
    v2f v2A = {vA.x * vA.x - vA.y * vA.y, 2.0f * vA.x * vA.y};
    v2f uB = {uBr, uBi};
    v2f vB = {vBr * elr - vBi * eli, vBr * eli + vBi * elr};
    v2f v2B = {vB.x * vB.x - vB.y * vB.y, 2.0f * vB.x * vB.y};
    v2f vC = {C128 * elr - S128 * eli, C128 * eli + S128 * elr};   // uC = -1
    v2f v2C = {vC.x * vC.x - vC.y * vC.y, 2.0f * vC.x * vC.y};

    v2f SA = {0,0}, SB = {0,0}, SC = {0,0};

    const float2* Xt = X + (size_t)t * 16 * 4096 + lane;
    const float*  wo = W + o * 144;     // block-uniform -> scalar loads

    v2f xbA, xbB, xbC;
    { float2 q = Xt[rA * 64]; xbA = (v2f){q.x, q.y}; }
    { float2 q = Xt[rB * 64]; xbB = (v2f){q.x, q.y}; }
    if (w == 0) { float2 q = Xt[32 * 64]; xbC = (v2f){q.x, q.y}; }
    #pragma unroll 1
    for (int c = 0; c < 16; ++c) {
        v2f xnA, xnB, xnC;
        if (c < 15) {
            { float2 q = Xt[(c + 1) * 4096 + rA * 64]; xnA = (v2f){q.x, q.y}; }
            { float2 q = Xt[(c + 1) * 4096 + rB * 64]; xnB = (v2f){q.x, q.y}; }
            if (w == 0) { float2 q = Xt[(c + 1) * 4096 + 32 * 64]; xnC = (v2f){q.x, q.y}; }
        }
        const float wa0 = wo[c*9+0], wa1 = wo[c*9+1], wa2 = wo[c*9+2];
        const float wa3 = wo[c*9+3], wa4 = wo[c*9+4], wa5 = wo[c*9+5];
        const float wa6 = wo[c*9+6], wa7 = wo[c*9+7], wa8 = wo[c*9+8];
        {   // slot A
            v2f h0 = (v2f){wa0, 0.0f}; h0 += vA * wa1; h0 += v2A * wa2;
            v2f h1 = (v2f){wa3, 0.0f}; h1 += vA * wa4; h1 += v2A * wa5;
            v2f h2 = (v2f){wa6, 0.0f}; h2 += vA * wa7; h2 += v2A * wa8;
            v2f P  = cmul_add(uA, cmul_add(uA, h2, h1), h0);
            SA = cmul_add(xbA, P, SA);
        }
        {   // slot B
            v2f h0 = (v2f){wa0, 0.0f}; h0 += vB * wa1; h0 += v2B * wa2;
            v2f h1 = (v2f){wa3, 0.0f}; h1 += vB * wa4; h1 += v2B * wa5;
            v2f h2 = (v2f){wa6, 0.0f}; h2 += vB * wa7; h2 += v2B * wa8;
            v2f P  = cmul_add(uB, cmul_add(uB, h2, h1), h0);
            SB = cmul_add(xbB, P, SB);
        }
        if (w == 0) {   // slot C, k1 = 32, u = -1 => P = h0 - h1 + h2
            v2f h0 = (v2f){wa0, 0.0f}; h0 += vC * wa1; h0 += v2C * wa2;
            v2f h1 = (v2f){wa3, 0.0f}; h1 += vC * wa4; h1 += v2C * wa5;
            v2f h2 = (v2f){wa6, 0.0f}; h2 += vC * wa7; h2 += v2C * wa8;
            v2f P  = h0 - h1 + h2;
            SC = cmul_add(xbC, P, SC);
        }
        xbA = xnA; xbB = xnB;
        if (w == 0) xbC = xnC;
    }

    // Publish half-spectrum S[k1][k2] (k1 <= 32) to LDS.
    sre[rA * PITCH + k2] = SA.x; sim[rA * PITCH + k2] = SA.y;
    sre[rB * PITCH + k2] = SB.x; sim[rB * PITCH + k2] = SB.y;
    if (w == 0) { sre[32 * PITCH + k2] = SC.x; sim[32 * PITCH + k2] = SC.y; }
    __syncthreads();

    // Gather 4 rows per thread (direct or Hermitian mirror).
    float re[RPW], im[RPW];
    #pragma unroll
    for (int m = 0; m < RPW; ++m) {
        int k1 = w * RPW + m;
        if (k1 <= 32) {
            re[m] = sre[k1 * PITCH + k2];
            im[m] = sim[k1 * PITCH + k2];
        } else {
            int k1p = 64 - k1, k2p = 63 - k2;
            re[m] =  sre[k1p * PITCH + k2p];
            im[m] = -sim[k1p * PITCH + k2p];
        }
    }
    __syncthreads();   // gather done before tail overwrites sre/sim

    // Phase 1: inverse FFT over k2 (lanes hold k2 = brev6(l) -> DIT).
    fft64_dit<RPW>(re, im, lane, +1.0f);
    // Mid twiddle: * e^{+2pi i n2 k1 / 4096}, n2 = lane, recurrence over m.
    {
        float cr, ci, sr, si;
        __sincosf((TWO_PI / 1024.0f) * (float)(lane * w), &ci, &cr);
        __sincosf((TWO_PI / 4096.0f) * (float)lane, &si, &sr);
        #pragma unroll
        for (int m = 0; m < RPW; ++m) {
            float rr = re[m] * cr - im[m] * ci;
            im[m]    = re[m] * ci + im[m] * cr;
            re[m]    = rr;
            float nr = cr * sr - ci * si;
            ci = cr * si + ci * sr; cr = nr;
        }
    }
    // Transpose through LDS: write [k1][n2].
    #pragma unroll
    for (int m = 0; m < RPW; ++m) {
        int k1 = w * RPW + m;
        sre[k1 * PITCH + lane] = re[m];
        sim[k1 * PITCH + lane] = im[m];
    }
    __syncthreads();
    // Phase 2: inverse FFT over k1 (lane = k1), columns n2 = w*4 + m.
    #pragma unroll
    for (int m = 0; m < RPW; ++m) {
        int n2 = w * RPW + m;
        re[m] = sre[lane * PITCH + n2];
        im[m] = sim[lane * PITCH + n2];
    }
    fft64_dif<RPW>(re, im, lane, +1.0f);
    __syncthreads();   // phase-2 reads done before y overwrite
    // Lane l holds y[n1 = brev6(l)][n2]; unscramble via LDS for coalesced store.
    const int n1 = brev6(lane);
    #pragma unroll
    for (int m = 0; m < RPW; ++m) {
        int n2 = w * RPW + m;
        sre[n1 * PITCH + n2] = re[m];
    }
    __syncthreads();
    const float bias = b[o];
    float* orow = out + (size_t)blockIdx.x * 62 * 62;
    for (int idx = tid; idx < 62 * 62; idx += NT) {
        int r = idx / 62, s = idx - r * 62;
        orow[idx] = sre[r * PITCH + s] * (1.0f / 4096.0f) + bias;
    }
}

extern "C" void kernel_launch(void* const* d_in, const int* in_sizes, int n_in,
                              void* d_out, int out_size, void* d_ws, size_t ws_size,
                              hipStream_t stream) {
    const float* x = (const float*)d_in[0];   // (8,16,62,62) f32
    const float* W = (const float*)d_in[1];   // (32,16,3,3)  f32
    const float* b = (const float*)d_in[2];   // (32,)        f32
    float* out = (float*)d_out;               // (8,32,62,62) f32
    float2* Xa = (float2*)d_ws;               // 128*4096 complex = 4 MB
    float2* X  = Xa + 128 * 4096;             // 4 MB more

    fwdA_kernel<<<dim3(256), dim3(NT), 0, stream>>>(x, Xa);
    fwdB_kernel<<<dim3(256), dim3(NT), 0, stream>>>(Xa, X);
    conv_kernel<<<dim3(256), dim3(NT), 0, stream>>>(X, W, b, out);
}

// Round 9
// 82.066 us; speedup vs baseline: 1.1719x; 1.0098x over previous
//
#include <hip/hip_runtime.h>
#include <math.h>

#define TWO_PI 6.28318530717958647692f
#define NT     1024          // 16 waves per block
#define RPW    4             // rows/cols per wave in iFFT tail (64 / 16 waves)
#define PITCH  65            // LDS pitch (odd -> conflict-free both ways)
#define THRESH 10.0f
// e^{2pi i/128} (for k1 = 32 row: e^{2pi i 32/4096})
#define C128   0.998795456205172393f
#define S128   0.049067674327418015f

typedef float v2f __attribute__((ext_vector_type(2)));

__device__ __forceinline__ int brev6(int x) {
    return (int)(__brev((unsigned)x) >> 26);
}

// acc + a*b (complex)
__device__ __forceinline__ v2f cmul_add(v2f a, v2f b, v2f acc) {
    acc += (v2f){a.x, a.x} * b;
    acc += (v2f){a.y, a.y} * (v2f){-b.y, b.x};
    return acc;
}

// Per-lane stage twiddles for the 64-pt cross-lane FFT (6 stages).
// t[s] = exp(sign * 2pi i * (lane & (2^s - 1)) * (32 >> s) / 64)
struct Tw6 { v2f t[6]; };

__device__ __forceinline__ Tw6 make_tw6(int lane, float sign) {
    Tw6 T;
    #pragma unroll
    for (int s = 0; s < 6; ++s) {
        int h = 1 << s;
        int j = lane & (h - 1);
        float ang = sign * (TWO_PI / 64.0f) * (float)(j * (32 >> s));
        float c, si;
        __sincosf(ang, &si, &c);
        T.t[s] = (v2f){c, si};
    }
    return T;
}

// Cross-lane 64-pt DIF FFT, precomputed twiddles. Natural-order input across
// lanes; output: lane l holds coefficient brev6(l).
template<int R>
__device__ __forceinline__ void fft64_dif_t(float (&re)[R], float (&im)[R],
                                            int lane, const Tw6& T) {
    #pragma unroll
    for (int s = 5; s >= 0; --s) {
        const int h = 1 << s;
        float wr = T.t[s].x, wi = T.t[s].y;
        bool upper = (lane & h) != 0;
        float cwr = upper ? wr : 1.0f;
        float cwi = upper ? wi : 0.0f;
        float sgn = upper ? -1.0f : 1.0f;
        #pragma unroll
        for (int m = 0; m < R; ++m) {
            float orr = __shfl_xor(re[m], h, 64);
            float oii = __shfl_xor(im[m], h, 64);
            float ar = fmaf(sgn, re[m], orr);
            float ai = fmaf(sgn, im[m], oii);
            re[m] = ar * cwr - ai * cwi;
            im[m] = ar * cwi + ai * cwr;
        }
    }
}

// Cross-lane 64-pt DIT FFT, precomputed twiddles. Bit-reversed input across
// lanes; natural-order output.
template<int R>
__device__ __forceinline__ void fft64_dit_t(float (&re)[R], float (&im)[R],
                                            int lane, const Tw6& T) {
    #pragma unroll
    for (int s = 0; s < 6; ++s) {
        const int h = 1 << s;
        float wr = T.t[s].x, wi = T.t[s].y;
        bool upper = (lane & h) != 0;
        float cwr = upper ? wr : 1.0f;
        float cwi = upper ? wi : 0.0f;
        float sgn = upper ? -1.0f : 1.0f;
        #pragma unroll
        for (int m = 0; m < R; ++m) {
            float tr = re[m] * cwr - im[m] * cwi;
            float ti = re[m] * cwi + im[m] * cwr;
            float orr = __shfl_xor(tr, h, 64);
            float oii = __shfl_xor(ti, h, 64);
            re[m] = fmaf(sgn, tr, orr);
            im[m] = fmaf(sgn, ti, oii);
        }
    }
}

// fwd: 128 blocks, one per (t,c). Pad 62x62 -> 64x64 in LDS; phase A: column
// FFT over n1 + mid twiddle, LDS transpose; phase B: row FFT over n2 for
// Hermitian rows k1 <= 32 only, threshold, store
// X[task][k1][l] = spectrum[k1 + 64*brev6(l)].
__global__ __launch_bounds__(NT) void fwd_kernel(const float* __restrict__ x,
                                                 float2* __restrict__ X) {
    __shared__ float sre[64 * PITCH];
    __shared__ float sim[64 * PITCH];
    const int task = blockIdx.x;
    const int tid  = threadIdx.x;
    const int lane = tid & 63;
    const int w    = tid >> 6;          // 0..15
    const float* xr = x + (size_t)task * 62 * 62;

    for (int idx = tid; idx < 4096; idx += NT) {
        int r = idx >> 6, s = idx & 63;
        float v = 0.0f;
        if (r >= 1 && r <= 62 && s >= 1 && s <= 62)
            v = xr[(r - 1) * 62 + (s - 1)];
        sre[r * PITCH + s] = v;
    }
    __syncthreads();

    const Tw6 Tf = make_tw6(lane, -1.0f);

    // Phase A: FFT over n1 (lane = n1), columns n2 = w*4 + m.
    float re[RPW], im[RPW];
    #pragma unroll
    for (int m = 0; m < RPW; ++m) {
        re[m] = sre[lane * PITCH + (w * RPW + m)];
        im[m] = 0.0f;
    }
    fft64_dif_t<RPW>(re, im, lane, Tf);
    const int k1 = brev6(lane);
    // Mid twiddle: * e^{-2pi i k1 n2 / 4096}
    #pragma unroll
    for (int m = 0; m < RPW; ++m) {
        int n2 = w * RPW + m;
        float cr, ci;
        __sincosf(-(TWO_PI / 4096.0f) * (float)(k1 * n2), &ci, &cr);
        float rr = re[m] * cr - im[m] * ci;
        im[m]    = re[m] * ci + im[m] * cr;
        re[m]    = rr;
    }
    __syncthreads();                 // all phase-A reads done before overwrite
    #pragma unroll
    for (int m = 0; m < RPW; ++m) {
        int n2 = w * RPW + m;
        sre[k1 * PITCH + n2] = re[m];
        sim[k1 * PITCH + n2] = im[m];
    }
    __syncthreads();

    // Phase B: rows 2w, 2w+1, 32 (slot C stored by wave 0 only).
    float rb[3], ib[3];
    const int rows[3] = {2 * w, 2 * w + 1, 32};
    #pragma unroll
    for (int s = 0; s < 3; ++s) {
        rb[s] = sre[rows[s] * PITCH + lane];
        ib[s] = sim[rows[s] * PITCH + lane];
    }
    fft64_dif_t<3>(rb, ib, lane, Tf);
    float2* Xrow = X + (size_t)task * 4096;
    #pragma unroll
    for (int s = 0; s < 3; ++s) {
        if (s < 2 || w == 0) {
            float rr = rb[s], ii = ib[s];
            if (fabsf(rr) < THRESH) { rr = 0.0f; ii = 0.0f; }
            Xrow[rows[s] * 64 + lane] = make_float2(rr, ii);
        }
    }
}

// conv: per (t,o). Hermitian-halved Q with 4-deep chunked prefetch; rows
// 33..63 reconstructed as conj via LDS; inverse four-step FFT; crop + bias.
__global__ __launch_bounds__(NT, 4) void conv_kernel(const float2* __restrict__ X,
                                                     const float* __restrict__ W,
                                                     const float* __restrict__ b,
                                                     float* __restrict__ out) {
    __shared__ float sre[64 * PITCH];
    __shared__ float sim[64 * PITCH];
    const int t    = blockIdx.x >> 5;
    const int o    = blockIdx.x & 31;
    const int tid  = threadIdx.x;
    const int lane = tid & 63;
    const int w    = tid >> 6;          // 0..15

    const int k2 = brev6(lane);
    float elr, eli;          // e^{+2pi i k2/64}
    __sincosf((TWO_PI / 64.0f) * (float)k2, &eli, &elr);

    const Tw6 Ti = make_tw6(lane, +1.0f);

    // Slot twiddles: A: k1=2w, B: k1=2w+1, C: k1=32 (wave 0 only).
    const int rA = 2 * w, rB = 2 * w + 1;
    float uAr, uAi, vAr, vAi, uBr, uBi, vBr, vBi;
    __sincosf((TWO_PI / 64.0f) * (float)rA, &uAi, &uAr);
    __sincosf((TWO_PI / 4096.0f) * (float)rA, &vAi, &vAr);
    __sincosf((TWO_PI / 64.0f) * (float)rB, &uBi, &uBr);
    __sincosf((TWO_PI / 4096.0f) * (float)rB, &vBi, &vBr);
    v2f uA = {uAr, uAi};
    v2f vA = {vAr * elr - vAi * eli, vAr * eli + vAi * elr};
    v2f v2A = {vA.x * vA.x - vA.y * vA.y, 2.0f * vA.x * vA.y};
    v2f uB = {uBr, uBi};
    v2f vB = {vBr * elr - vBi * eli, vBr * eli + vBi * elr};
    v2f v2B = {vB.x * vB.x - vB.y * vB.y, 2.0f * vB.x * vB.y};
    v2f vC = {C128 * elr - S128 * eli, C128 * eli + S128 * elr};   // uC = -1
    v2f v2C = {vC.x * vC.x - vC.y * vC.y, 2.0f * vC.x * vC.y};

    v2f SA = {0,0}, SB = {0,0}, SC = {0,0};

    const float2* Xt = X + (size_t)t * 16 * 4096 + lane;
    const float*  wo = W + o * 144;     // block-uniform -> scalar loads

    // Chunked c-loop: 4 chunks of 4; loads for chunk cc+1 issued before
    // computing chunk cc (4 exposed latencies instead of 16).
    v2f xA[4], xB[4], xC[4];
    #pragma unroll
    for (int j = 0; j < 4; ++j) {
        { float2 q = Xt[j * 4096 + rA * 64]; xA[j] = (v2f){q.x, q.y}; }
        { float2 q = Xt[j * 4096 + rB * 64]; xB[j] = (v2f){q.x, q.y}; }
    }
    if (w == 0) {
        #pragma unroll
        for (int j = 0; j < 4; ++j) {
            float2 q = Xt[j * 4096 + 32 * 64]; xC[j] = (v2f){q.x, q.y};
        }
    }
    #pragma unroll 1
    for (int cc = 0; cc < 4; ++cc) {
        v2f nA[4], nB[4], nC[4];
        if (cc < 3) {
            const float2* xp = Xt + (cc + 1) * 4 * 4096;
            #pragma unroll
            for (int j = 0; j < 4; ++j) {
                { float2 q = xp[j * 4096 + rA * 64]; nA[j] = (v2f){q.x, q.y}; }
                { float2 q = xp[j * 4096 + rB * 64]; nB[j] = (v2f){q.x, q.y}; }
            }
            if (w == 0) {
                #pragma unroll
                for (int j = 0; j < 4; ++j) {
                    float2 q = xp[j * 4096 + 32 * 64]; nC[j] = (v2f){q.x, q.y};
                }
            }
        }
        #pragma unroll
        for (int j = 0; j < 4; ++j) {
            const float* wc = wo + (cc * 4 + j) * 9;
            const float wa0 = wc[0], wa1 = wc[1], wa2 = wc[2];
            const float wa3 = wc[3], wa4 = wc[4], wa5 = wc[5];
            const float wa6 = wc[6], wa7 = wc[7], wa8 = wc[8];
            {   // slot A
                v2f h0 = (v2f){wa0, 0.0f}; h0 += vA * wa1; h0 += v2A * wa2;
                v2f h1 = (v2f){wa3, 0.0f}; h1 += vA * wa4; h1 += v2A * wa5;
                v2f h2 = (v2f){wa6, 0.0f}; h2 += vA * wa7; h2 += v2A * wa8;
                v2f P  = cmul_add(uA, cmul_add(uA, h2, h1), h0);
                SA = cmul_add(xA[j], P, SA);
            }
            {   // slot B
                v2f h0 = (v2f){wa0, 0.0f}; h0 += vB * wa1; h0 += v2B * wa2;
                v2f h1 = (v2f){wa3, 0.0f}; h1 += vB * wa4; h1 += v2B * wa5;
                v2f h2 = (v2f){wa6, 0.0f}; h2 += vB * wa7; h2 += v2B * wa8;
                v2f P  = cmul_add(uB, cmul_add(uB, h2, h1), h0);
                SB = cmul_add(xB[j], P, SB);
            }
            if (w == 0) {   // slot C, k1 = 32, u = -1 => P = h0 - h1 + h2
                v2f h0 = (v2f){wa0, 0.0f}; h0 += vC * wa1; h0 += v2C * wa2;
                v2f h1 = (v2f){wa3, 0.0f}; h1 += vC * wa4; h1 += v2C * wa5;
                v2f h2 = (v2f){wa6, 0.0f}; h2 += vC * wa7; h2 += v2C * wa8;
                v2f P  = h0 - h1 + h2;
                SC = cmul_add(xC[j], P, SC);
            }
        }
        #pragma unroll
        for (int j = 0; j < 4; ++j) { xA[j] = nA[j]; xB[j] = nB[j]; }
        if (w == 0) {
            #pragma unroll
            for (int j = 0; j < 4; ++j) xC[j] = nC[j];
        }
    }

    // Publish half-spectrum S[k1][k2] (k1 <= 32) to LDS.
    sre[rA * PITCH + k2] = SA.x; sim[rA * PITCH + k2] = SA.y;
    sre[rB * PITCH + k2] = SB.x; sim[rB * PITCH + k2] = SB.y;
    if (w == 0) { sre[32 * PITCH + k2] = SC.x; sim[32 * PITCH + k2] = SC.y; }
    __syncthreads();

    // Gather 4 rows per thread (direct or Hermitian mirror).
    float re[RPW], im[RPW];
    #pragma unroll
    for (int m = 0; m < RPW; ++m) {
        int k1 = w * RPW + m;
        if (k1 <= 32) {
            re[m] = sre[k1 * PITCH + k2];
            im[m] = sim[k1 * PITCH + k2];
        } else {
            int k1p = 64 - k1, k2p = 63 - k2;
            re[m] =  sre[k1p * PITCH + k2p];
            im[m] = -sim[k1p * PITCH + k2p];
        }
    }
    __syncthreads();   // gather done before tail overwrites sre/sim

    // Phase 1: inverse FFT over k2 (lanes hold k2 = brev6(l) -> DIT).
    fft64_dit_t<RPW>(re, im, lane, Ti);
    // Mid twiddle: * e^{+2pi i n2 k1 / 4096}, n2 = lane, recurrence over m.
    {
        float cr, ci, sr, si;
        __sincosf((TWO_PI / 1024.0f) * (float)(lane * w), &ci, &cr);
        __sincosf((TWO_PI / 4096.0f) * (float)lane, &si, &sr);
        #pragma unroll
        for (int m = 0; m < RPW; ++m) {
            float rr = re[m] * cr - im[m] * ci;
            im[m]    = re[m] * ci + im[m] * cr;
            re[m]    = rr;
            float nr = cr * sr - ci * si;
            ci = cr * si + ci * sr; cr = nr;
        }
    }
    // Transpose through LDS: write [k1][n2].
    #pragma unroll
    for (int m = 0; m < RPW; ++m) {
        int k1 = w * RPW + m;
        sre[k1 * PITCH + lane] = re[m];
        sim[k1 * PITCH + lane] = im[m];
    }
    __syncthreads();
    // Phase 2: inverse FFT over k1 (lane = k1), columns n2 = w*4 + m.
    #pragma unroll
    for (int m = 0; m < RPW; ++m) {
        int n2 = w * RPW + m;
        re[m] = sre[lane * PITCH + n2];
        im[m] = sim[lane * PITCH + n2];
    }
    fft64_dif_t<RPW>(re, im, lane, Ti);
    __syncthreads();   // phase-2 reads done before y overwrite
    // Lane l holds y[n1 = brev6(l)][n2]; unscramble via LDS for coalesced store.
    const int n1 = brev6(lane);
    #pragma unroll
    for (int m = 0; m < RPW; ++m) {
        int n2 = w * RPW + m;
        sre[n1 * PITCH + n2] = re[m];
    }
    __syncthreads();
    const float bias = b[o];
    float* orow = out + (size_t)blockIdx.x * 62 * 62;
    for (int idx = tid; idx < 62 * 62; idx += NT) {
        int r = idx / 62, s = idx - r * 62;
        orow[idx] = sre[r * PITCH + s] * (1.0f / 4096.0f) + bias;
    }
}

extern "C" void kernel_launch(void* const* d_in, const int* in_sizes, int n_in,
                              void* d_out, int out_size, void* d_ws, size_t ws_size,
                              hipStream_t stream) {
    const float* x = (const float*)d_in[0];   // (8,16,62,62) f32
    const float* W = (const float*)d_in[1];   // (32,16,3,3)  f32
    const float* b = (const float*)d_in[2];   // (32,)        f32
    float* out = (float*)d_out;               // (8,32,62,62) f32
    float2* X = (float2*)d_ws;                // 128*4096 complex = 4 MB

    fwd_kernel<<<dim3(128), dim3(NT), 0, stream>>>(x, X);
    conv_kernel<<<dim3(256), dim3(NT), 0, stream>>>(X, W, b, out);
}

// Round 10
// 79.518 us; speedup vs baseline: 1.2095x; 1.0321x over previous
//
#include <hip/hip_runtime.h>
#include <math.h>

#define TWO_PI 6.28318530717958647692f
#define NT     1024          // 16 waves per block
#define RPW    4             // rows/cols per wave in iFFT tail (64 / 16 waves)
#define PITCH  65            // LDS pitch (odd -> conflict-free both ways)
#define THRESH 10.0f
// e^{2pi i/128} (for k1 = 32 row: e^{2pi i 32/4096})
#define C128   0.998795456205172393f
#define S128   0.049067674327418015f

typedef float v2f __attribute__((ext_vector_type(2)));

__device__ __forceinline__ int brev6(int x) {
    return (int)(__brev((unsigned)x) >> 26);
}

// acc + a*b (complex)
__device__ __forceinline__ v2f cmul_add(v2f a, v2f b, v2f acc) {
    acc += (v2f){a.x, a.x} * b;
    acc += (v2f){a.y, a.y} * (v2f){-b.y, b.x};
    return acc;
}

// Per-lane stage twiddles for the 64-pt cross-lane FFT (6 stages).
struct Tw6 { v2f t[6]; };

__device__ __forceinline__ Tw6 make_tw6(int lane, float sign) {
    Tw6 T;
    #pragma unroll
    for (int s = 0; s < 6; ++s) {
        int h = 1 << s;
        int j = lane & (h - 1);
        float ang = sign * (TWO_PI / 64.0f) * (float)(j * (32 >> s));
        float c, si;
        __sincosf(ang, &si, &c);
        T.t[s] = (v2f){c, si};
    }
    return T;
}

// Cross-lane 64-pt DIF FFT, precomputed twiddles. Natural-order input across
// lanes; output: lane l holds coefficient brev6(l).
template<int R>
__device__ __forceinline__ void fft64_dif_t(float (&re)[R], float (&im)[R],
                                            int lane, const Tw6& T) {
    #pragma unroll
    for (int s = 5; s >= 0; --s) {
        const int h = 1 << s;
        float wr = T.t[s].x, wi = T.t[s].y;
        bool upper = (lane & h) != 0;
        float cwr = upper ? wr : 1.0f;
        float cwi = upper ? wi : 0.0f;
        float sgn = upper ? -1.0f : 1.0f;
        #pragma unroll
        for (int m = 0; m < R; ++m) {
            float orr = __shfl_xor(re[m], h, 64);
            float oii = __shfl_xor(im[m], h, 64);
            float ar = fmaf(sgn, re[m], orr);
            float ai = fmaf(sgn, im[m], oii);
            re[m] = ar * cwr - ai * cwi;
            im[m] = ar * cwi + ai * cwr;
        }
    }
}

// Cross-lane 64-pt DIT FFT, precomputed twiddles. Bit-reversed input across
// lanes; natural-order output.
template<int R>
__device__ __forceinline__ void fft64_dit_t(float (&re)[R], float (&im)[R],
                                            int lane, const Tw6& T) {
    #pragma unroll
    for (int s = 0; s < 6; ++s) {
        const int h = 1 << s;
        float wr = T.t[s].x, wi = T.t[s].y;
        bool upper = (lane & h) != 0;
        float cwr = upper ? wr : 1.0f;
        float cwi = upper ? wi : 0.0f;
        float sgn = upper ? -1.0f : 1.0f;
        #pragma unroll
        for (int m = 0; m < R; ++m) {
            float tr = re[m] * cwr - im[m] * cwi;
            float ti = re[m] * cwi + im[m] * cwr;
            float orr = __shfl_xor(tr, h, 64);
            float oii = __shfl_xor(ti, h, 64);
            re[m] = fmaf(sgn, tr, orr);
            im[m] = fmaf(sgn, ti, oii);
        }
    }
}

// S = sum_q T[q] * u^i v^j  (q = 3i + j), double Horner.
__device__ __forceinline__ v2f tap_combine(const v2f (&T)[9], v2f u, v2f v,
                                           v2f v2) {
    v2f g0 = cmul_add(v2, T[2], cmul_add(v, T[1], T[0]));
    v2f g1 = cmul_add(v2, T[5], cmul_add(v, T[4], T[3]));
    v2f g2 = cmul_add(v2, T[8], cmul_add(v, T[7], T[6]));
    return cmul_add(u, cmul_add(u, g2, g1), g0);
}

// fwd: 128 blocks, one per (t,c). Pad 62x62 -> 64x64 in LDS; phase A: column
// FFT over n1 + mid twiddle, LDS transpose; phase B: row FFT over n2 for
// Hermitian rows k1 <= 32 only, threshold, store
// X[task][k1][l] = spectrum[k1 + 64*brev6(l)].
__global__ __launch_bounds__(NT) void fwd_kernel(const float* __restrict__ x,
                                                 float2* __restrict__ X) {
    __shared__ float sre[64 * PITCH];
    __shared__ float sim[64 * PITCH];
    const int task = blockIdx.x;
    const int tid  = threadIdx.x;
    const int lane = tid & 63;
    const int w    = tid >> 6;          // 0..15
    const float* xr = x + (size_t)task * 62 * 62;

    for (int idx = tid; idx < 4096; idx += NT) {
        int r = idx >> 6, s = idx & 63;
        float v = 0.0f;
        if (r >= 1 && r <= 62 && s >= 1 && s <= 62)
            v = xr[(r - 1) * 62 + (s - 1)];
        sre[r * PITCH + s] = v;
    }
    __syncthreads();

    const Tw6 Tf = make_tw6(lane, -1.0f);

    // Phase A: FFT over n1 (lane = n1), columns n2 = w*4 + m.
    float re[RPW], im[RPW];
    #pragma unroll
    for (int m = 0; m < RPW; ++m) {
        re[m] = sre[lane * PITCH + (w * RPW + m)];
        im[m] = 0.0f;
    }
    fft64_dif_t<RPW>(re, im, lane, Tf);
    const int k1 = brev6(lane);
    // Mid twiddle: * e^{-2pi i k1 n2 / 4096}
    #pragma unroll
    for (int m = 0; m < RPW; ++m) {
        int n2 = w * RPW + m;
        float cr, ci;
        __sincosf(-(TWO_PI / 4096.0f) * (float)(k1 * n2), &ci, &cr);
        float rr = re[m] * cr - im[m] * ci;
        im[m]    = re[m] * ci + im[m] * cr;
        re[m]    = rr;
    }
    __syncthreads();                 // all phase-A reads done before overwrite
    #pragma unroll
    for (int m = 0; m < RPW; ++m) {
        int n2 = w * RPW + m;
        sre[k1 * PITCH + n2] = re[m];
        sim[k1 * PITCH + n2] = im[m];
    }
    __syncthreads();

    // Phase B: rows 2w, 2w+1, 32 (slot C stored by wave 0 only).
    float rb[3], ib[3];
    const int rows[3] = {2 * w, 2 * w + 1, 32};
    #pragma unroll
    for (int s = 0; s < 3; ++s) {
        rb[s] = sre[rows[s] * PITCH + lane];
        ib[s] = sim[rows[s] * PITCH + lane];
    }
    fft64_dif_t<3>(rb, ib, lane, Tf);
    float2* Xrow = X + (size_t)task * 4096;
    #pragma unroll
    for (int s = 0; s < 3; ++s) {
        if (s < 2 || w == 0) {
            float rr = rb[s], ii = ib[s];
            if (fabsf(rr) < THRESH) { rr = 0.0f; ii = 0.0f; }
            Xrow[rows[s] * 64 + lane] = make_float2(rr, ii);
        }
    }
}

// conv: per (t,o). Hermitian-halved tap accumulation with ALL channel loads
// issued upfront (one exposed latency); rows 33..63 reconstructed as conj via
// LDS; inverse four-step FFT; crop + bias.
__global__ __launch_bounds__(NT, 3) void conv_kernel(const float2* __restrict__ X,
                                                     const float* __restrict__ W,
                                                     const float* __restrict__ b,
                                                     float* __restrict__ out) {
    __shared__ float sre[64 * PITCH];
    __shared__ float sim[64 * PITCH];
    const int t    = blockIdx.x >> 5;
    const int o    = blockIdx.x & 31;
    const int tid  = threadIdx.x;
    const int lane = tid & 63;
    const int w    = tid >> 6;          // 0..15

    const int k2 = brev6(lane);
    float elr, eli;          // e^{+2pi i k2/64}
    __sincosf((TWO_PI / 64.0f) * (float)k2, &eli, &elr);

    const Tw6 Ti = make_tw6(lane, +1.0f);

    // Slot twiddles: A: k1=2w, B: k1=2w+1.
    const int rA = 2 * w, rB = 2 * w + 1;
    float uAr, uAi, vAr, vAi, uBr, uBi, vBr, vBi;
    __sincosf((TWO_PI / 64.0f) * (float)rA, &uAi, &uAr);
    __sincosf((TWO_PI / 4096.0f) * (float)rA, &vAi, &vAr);
    __sincosf((TWO_PI / 64.0f) * (float)rB, &uBi, &uBr);
    __sincosf((TWO_PI / 4096.0f) * (float)rB, &vBi, &vBr);
    v2f uA = {uAr, uAi};
    v2f vA = {vAr * elr - vAi * eli, vAr * eli + vAi * elr};
    v2f v2A = {vA.x * vA.x - vA.y * vA.y, 2.0f * vA.x * vA.y};
    v2f uB = {uBr, uBi};
    v2f vB = {vBr * elr - vBi * eli, vBr * eli + vBi * elr};
    v2f v2B = {vB.x * vB.x - vB.y * vB.y, 2.0f * vB.x * vB.y};

    const float2* Xt = X + (size_t)t * 16 * 4096 + lane;
    const float*  wo = W + o * 144;     // block-uniform -> scalar loads

    // Issue ALL 32 loads upfront (16 channels x 2 slots) -> one exposed
    // latency instead of a serial chain.
    v2f xA[16], xB[16];
    #pragma unroll
    for (int c = 0; c < 16; ++c) {
        { float2 q = Xt[c * 4096 + rA * 64]; xA[c] = (v2f){q.x, q.y}; }
        { float2 q = Xt[c * 4096 + rB * 64]; xB[c] = (v2f){q.x, q.y}; }
    }
    // Tap accumulation: T[q] = sum_c W[c,q] * X[c]  (pure FMA, 9 accumulators)
    v2f TA[9], TB[9];
    #pragma unroll
    for (int q = 0; q < 9; ++q) { TA[q] = (v2f){0,0}; TB[q] = (v2f){0,0}; }
    #pragma unroll
    for (int c = 0; c < 16; ++c) {
        const float* wc = wo + c * 9;
        #pragma unroll
        for (int q = 0; q < 9; ++q) {
            float wq = wc[q];
            TA[q] += xA[c] * wq;
            TB[q] += xB[c] * wq;
        }
    }
    v2f SA = tap_combine(TA, uA, vA, v2A);
    v2f SB = tap_combine(TB, uB, vB, v2B);

    // Publish half-spectrum rows rA, rB to LDS.
    sre[rA * PITCH + k2] = SA.x; sim[rA * PITCH + k2] = SA.y;
    sre[rB * PITCH + k2] = SB.x; sim[rB * PITCH + k2] = SB.y;

    // Row 32 post-pass (wave 0 only): u = -1, v = e^{2pi i/128} * el.
    if (w == 0) {
        v2f xC[16];
        #pragma unroll
        for (int c = 0; c < 16; ++c) {
            float2 q = Xt[c * 4096 + 32 * 64]; xC[c] = (v2f){q.x, q.y};
        }
        v2f TC[9];
        #pragma unroll
        for (int q = 0; q < 9; ++q) TC[q] = (v2f){0,0};
        #pragma unroll
        for (int c = 0; c < 16; ++c) {
            const float* wc = wo + c * 9;
            #pragma unroll
            for (int q = 0; q < 9; ++q) TC[q] += xC[c] * wc[q];
        }
        v2f vC = {C128 * elr - S128 * eli, C128 * eli + S128 * elr};
        v2f v2C = {vC.x * vC.x - vC.y * vC.y, 2.0f * vC.x * vC.y};
        v2f g0 = cmul_add(v2C, TC[2], cmul_add(vC, TC[1], TC[0]));
        v2f g1 = cmul_add(v2C, TC[5], cmul_add(vC, TC[4], TC[3]));
        v2f g2 = cmul_add(v2C, TC[8], cmul_add(vC, TC[7], TC[6]));
        v2f SC = g0 - g1 + g2;
        sre[32 * PITCH + k2] = SC.x; sim[32 * PITCH + k2] = SC.y;
    }
    __syncthreads();

    // Gather 4 rows per thread (direct or Hermitian mirror).
    float re[RPW], im[RPW];
    #pragma unroll
    for (int m = 0; m < RPW; ++m) {
        int k1 = w * RPW + m;
        if (k1 <= 32) {
            re[m] = sre[k1 * PITCH + k2];
            im[m] = sim[k1 * PITCH + k2];
        } else {
            int k1p = 64 - k1, k2p = 63 - k2;
            re[m] =  sre[k1p * PITCH + k2p];
            im[m] = -sim[k1p * PITCH + k2p];
        }
    }
    __syncthreads();   // gather done before tail overwrites sre/sim

    // Phase 1: inverse FFT over k2 (lanes hold k2 = brev6(l) -> DIT).
    fft64_dit_t<RPW>(re, im, lane, Ti);
    // Mid twiddle: * e^{+2pi i n2 k1 / 4096}, n2 = lane (independent sincos).
    #pragma unroll
    for (int m = 0; m < RPW; ++m) {
        int k1 = w * RPW + m;
        float cr, ci;
        __sincosf((TWO_PI / 4096.0f) * (float)(lane * k1), &ci, &cr);
        float rr = re[m] * cr - im[m] * ci;
        im[m]    = re[m] * ci + im[m] * cr;
        re[m]    = rr;
    }
    // Transpose through LDS: write [k1][n2].
    #pragma unroll
    for (int m = 0; m < RPW; ++m) {
        int k1 = w * RPW + m;
        sre[k1 * PITCH + lane] = re[m];
        sim[k1 * PITCH + lane] = im[m];
    }
    __syncthreads();
    // Phase 2: inverse FFT over k1 (lane = k1), columns n2 = w*4 + m.
    #pragma unroll
    for (int m = 0; m < RPW; ++m) {
        int n2 = w * RPW + m;
        re[m] = sre[lane * PITCH + n2];
        im[m] = sim[lane * PITCH + n2];
    }
    fft64_dif_t<RPW>(re, im, lane, Ti);
    __syncthreads();   // phase-2 reads done before y overwrite
    // Lane l holds y[n1 = brev6(l)][n2]; unscramble via LDS for coalesced store.
    const int n1 = brev6(lane);
    #pragma unroll
    for (int m = 0; m < RPW; ++m) {
        int n2 = w * RPW + m;
        sre[n1 * PITCH + n2] = re[m];
    }
    __syncthreads();
    const float bias = b[o];
    float* orow = out + (size_t)blockIdx.x * 62 * 62;
    for (int idx = tid; idx < 62 * 62; idx += NT) {
        int r = idx / 62, s = idx - r * 62;
        orow[idx] = sre[r * PITCH + s] * (1.0f / 4096.0f) + bias;
    }
}

extern "C" void kernel_launch(void* const* d_in, const int* in_sizes, int n_in,
                              void* d_out, int out_size, void* d_ws, size_t ws_size,
                              hipStream_t stream) {
    const float* x = (const float*)d_in[0];   // (8,16,62,62) f32
    const float* W = (const float*)d_in[1];   // (32,16,3,3)  f32
    const float* b = (const float*)d_in[2];   // (32,)        f32
    float* out = (float*)d_out;               // (8,32,62,62) f32
    float2* X = (float2*)d_ws;                // 128*4096 complex = 4 MB

    fwd_kernel<<<dim3(128), dim3(NT), 0, stream>>>(x, X);
    conv_kernel<<<dim3(256), dim3(NT), 0, stream>>>(X, W, b, out);
}

// Round 11
// 76.176 us; speedup vs baseline: 1.2626x; 1.0439x over previous
//
#include <hip/hip_runtime.h>
#include <math.h>

#define TWO_PI 6.28318530717958647692f
#define NT     1024          // 16 waves per block
#define RPW    4             // rows/cols per wave in FFT phases (64 / 16 waves)
#define PITCH  65            // LDS pitch (odd -> conflict-free both ways)
#define THRESH 10.0f
// e^{2pi i/128} (for k1 = 32 row: e^{2pi i 32/4096})
#define C128   0.998795456205172393f
#define S128   0.049067674327418015f

typedef float v2f __attribute__((ext_vector_type(2)));

__device__ __forceinline__ int brev6(int x) {
    return (int)(__brev((unsigned)x) >> 26);
}

// acc + a*b (complex)
__device__ __forceinline__ v2f cmul_add(v2f a, v2f b, v2f acc) {
    acc += (v2f){a.x, a.x} * b;
    acc += (v2f){a.y, a.y} * (v2f){-b.y, b.x};
    return acc;
}

// Per-lane stage twiddles for the 64-pt cross-lane FFT (6 stages).
struct Tw6 { v2f t[6]; };

__device__ __forceinline__ Tw6 make_tw6(int lane, float sign) {
    Tw6 T;
    #pragma unroll
    for (int s = 0; s < 6; ++s) {
        int h = 1 << s;
        int j = lane & (h - 1);
        float ang = sign * (TWO_PI / 64.0f) * (float)(j * (32 >> s));
        float c, si;
        __sincosf(ang, &si, &c);
        T.t[s] = (v2f){c, si};
    }
    return T;
}

// Cross-lane 64-pt DIF FFT, precomputed twiddles. Natural-order input across
// lanes; output: lane l holds coefficient brev6(l).
template<int R>
__device__ __forceinline__ void fft64_dif_t(float (&re)[R], float (&im)[R],
                                            int lane, const Tw6& T) {
    #pragma unroll
    for (int s = 5; s >= 0; --s) {
        const int h = 1 << s;
        float wr = T.t[s].x, wi = T.t[s].y;
        bool upper = (lane & h) != 0;
        float cwr = upper ? wr : 1.0f;
        float cwi = upper ? wi : 0.0f;
        float sgn = upper ? -1.0f : 1.0f;
        #pragma unroll
        for (int m = 0; m < R; ++m) {
            float orr = __shfl_xor(re[m], h, 64);
            float oii = __shfl_xor(im[m], h, 64);
            float ar = fmaf(sgn, re[m], orr);
            float ai = fmaf(sgn, im[m], oii);
            re[m] = ar * cwr - ai * cwi;
            im[m] = ar * cwi + ai * cwr;
        }
    }
}

// Cross-lane 64-pt DIT FFT, precomputed twiddles. Bit-reversed input across
// lanes; natural-order output.
template<int R>
__device__ __forceinline__ void fft64_dit_t(float (&re)[R], float (&im)[R],
                                            int lane, const Tw6& T) {
    #pragma unroll
    for (int s = 0; s < 6; ++s) {
        const int h = 1 << s;
        float wr = T.t[s].x, wi = T.t[s].y;
        bool upper = (lane & h) != 0;
        float cwr = upper ? wr : 1.0f;
        float cwi = upper ? wi : 0.0f;
        float sgn = upper ? -1.0f : 1.0f;
        #pragma unroll
        for (int m = 0; m < R; ++m) {
            float tr = re[m] * cwr - im[m] * cwi;
            float ti = re[m] * cwi + im[m] * cwr;
            float orr = __shfl_xor(tr, h, 64);
            float oii = __shfl_xor(ti, h, 64);
            re[m] = fmaf(sgn, tr, orr);
            im[m] = fmaf(sgn, ti, oii);
        }
    }
}

// S = sum_q T[q] * u^i v^j  (q = 3i + j), double Horner.
__device__ __forceinline__ v2f tap_combine(const v2f (&T)[9], v2f u, v2f v,
                                           v2f v2) {
    v2f g0 = cmul_add(v2, T[2], cmul_add(v, T[1], T[0]));
    v2f g1 = cmul_add(v2, T[5], cmul_add(v, T[4], T[3]));
    v2f g2 = cmul_add(v2, T[8], cmul_add(v, T[7], T[6]));
    return cmul_add(u, cmul_add(u, g2, g1), g0);
}

// fwd: 256 blocks. Block b: t = b&7 (XCD-pin), r = b>>3, c = r&15, h = r>>4.
// Both h-blocks of a task redo phase A (cheap, full-machine tradeoff); phase
// B's Hermitian rows k1<=32 are split: h=0 -> rows 0..15, h=1 -> 16..31 + 32.
// Store X[task][k1][l] = spectrum[k1 + 64*brev6(l)].
__global__ __launch_bounds__(NT) void fwd_kernel(const float* __restrict__ x,
                                                 float2* __restrict__ X) {
    __shared__ float sre[64 * PITCH];
    __shared__ float sim[64 * PITCH];
    const int bId  = blockIdx.x;
    const int t    = bId & 7;
    const int rr_  = bId >> 3;
    const int c    = rr_ & 15;
    const int h    = rr_ >> 4;
    const int task = t * 16 + c;
    const int tid  = threadIdx.x;
    const int lane = tid & 63;
    const int w    = tid >> 6;          // 0..15
    const float* xr = x + (size_t)task * 62 * 62;

    for (int idx = tid; idx < 4096; idx += NT) {
        int r = idx >> 6, s = idx & 63;
        float v = 0.0f;
        if (r >= 1 && r <= 62 && s >= 1 && s <= 62)
            v = xr[(r - 1) * 62 + (s - 1)];
        sre[r * PITCH + s] = v;
    }
    __syncthreads();

    const Tw6 Tf = make_tw6(lane, -1.0f);

    // Phase A (redundant in both h-blocks): FFT over n1, columns n2 = w*4+m.
    float re[RPW], im[RPW];
    #pragma unroll
    for (int m = 0; m < RPW; ++m) {
        re[m] = sre[lane * PITCH + (w * RPW + m)];
        im[m] = 0.0f;
    }
    fft64_dif_t<RPW>(re, im, lane, Tf);
    const int k1 = brev6(lane);
    // Mid twiddle: * e^{-2pi i k1 n2 / 4096}
    #pragma unroll
    for (int m = 0; m < RPW; ++m) {
        int n2 = w * RPW + m;
        float cr, ci;
        __sincosf(-(TWO_PI / 4096.0f) * (float)(k1 * n2), &ci, &cr);
        float rv = re[m] * cr - im[m] * ci;
        im[m]    = re[m] * ci + im[m] * cr;
        re[m]    = rv;
    }
    __syncthreads();                 // all phase-A reads done before overwrite
    #pragma unroll
    for (int m = 0; m < RPW; ++m) {
        int n2 = w * RPW + m;
        sre[k1 * PITCH + n2] = re[m];
        sim[k1 * PITCH + n2] = im[m];
    }
    __syncthreads();

    // Phase B: 1 row per wave (+ row 32 slot, stored by h=1 wave 0 only).
    float rb[2], ib[2];
    const int row0 = 16 * h + w;
    rb[0] = sre[row0 * PITCH + lane];
    ib[0] = sim[row0 * PITCH + lane];
    rb[1] = sre[32 * PITCH + lane];
    ib[1] = sim[32 * PITCH + lane];
    fft64_dif_t<2>(rb, ib, lane, Tf);
    float2* Xrow = X + (size_t)task * 4096;
    {
        float rv = rb[0], iv = ib[0];
        if (fabsf(rv) < THRESH) { rv = 0.0f; iv = 0.0f; }
        Xrow[row0 * 64 + lane] = make_float2(rv, iv);
    }
    if (h == 1 && w == 0) {
        float rv = rb[1], iv = ib[1];
        if (fabsf(rv) < THRESH) { rv = 0.0f; iv = 0.0f; }
        Xrow[32 * 64 + lane] = make_float2(rv, iv);
    }
}

// conv: block b: t = b&7 (same-XCD as fwd's X[t] producers -> L2-local reads),
// o = b>>3. Hermitian-halved tap accumulation, all loads upfront; inverse
// four-step FFT; crop + bias.
__global__ __launch_bounds__(NT, 3) void conv_kernel(const float2* __restrict__ X,
                                                     const float* __restrict__ W,
                                                     const float* __restrict__ b,
                                                     float* __restrict__ out) {
    __shared__ float sre[64 * PITCH];
    __shared__ float sim[64 * PITCH];
    const int t    = blockIdx.x & 7;
    const int o    = blockIdx.x >> 3;
    const int tid  = threadIdx.x;
    const int lane = tid & 63;
    const int w    = tid >> 6;          // 0..15

    const int k2 = brev6(lane);
    float elr, eli;          // e^{+2pi i k2/64}
    __sincosf((TWO_PI / 64.0f) * (float)k2, &eli, &elr);

    const Tw6 Ti = make_tw6(lane, +1.0f);

    // Slot twiddles: A: k1=2w, B: k1=2w+1.
    const int rA = 2 * w, rB = 2 * w + 1;
    float uAr, uAi, vAr, vAi, uBr, uBi, vBr, vBi;
    __sincosf((TWO_PI / 64.0f) * (float)rA, &uAi, &uAr);
    __sincosf((TWO_PI / 4096.0f) * (float)rA, &vAi, &vAr);
    __sincosf((TWO_PI / 64.0f) * (float)rB, &uBi, &uBr);
    __sincosf((TWO_PI / 4096.0f) * (float)rB, &vBi, &vBr);
    v2f uA = {uAr, uAi};
    v2f vA = {vAr * elr - vAi * eli, vAr * eli + vAi * elr};
    v2f v2A = {vA.x * vA.x - vA.y * vA.y, 2.0f * vA.x * vA.y};
    v2f uB = {uBr, uBi};
    v2f vB = {vBr * elr - vBi * eli, vBr * eli + vBi * elr};
    v2f v2B = {vB.x * vB.x - vB.y * vB.y, 2.0f * vB.x * vB.y};

    const float2* Xt = X + (size_t)t * 16 * 4096 + lane;
    const float*  wo = W + o * 144;     // block-uniform -> scalar loads

    // Issue ALL 32 loads upfront (16 channels x 2 slots).
    v2f xA[16], xB[16];
    #pragma unroll
    for (int c = 0; c < 16; ++c) {
        { float2 q = Xt[c * 4096 + rA * 64]; xA[c] = (v2f){q.x, q.y}; }
        { float2 q = Xt[c * 4096 + rB * 64]; xB[c] = (v2f){q.x, q.y}; }
    }
    // Tap accumulation: T[q] = sum_c W[c,q] * X[c]  (pure FMA, 9 accumulators)
    v2f TA[9], TB[9];
    #pragma unroll
    for (int q = 0; q < 9; ++q) { TA[q] = (v2f){0,0}; TB[q] = (v2f){0,0}; }
    #pragma unroll
    for (int c = 0; c < 16; ++c) {
        const float* wc = wo + c * 9;
        #pragma unroll
        for (int q = 0; q < 9; ++q) {
            float wq = wc[q];
            TA[q] += xA[c] * wq;
            TB[q] += xB[c] * wq;
        }
    }
    v2f SA = tap_combine(TA, uA, vA, v2A);
    v2f SB = tap_combine(TB, uB, vB, v2B);

    // Publish half-spectrum rows rA, rB to LDS.
    sre[rA * PITCH + k2] = SA.x; sim[rA * PITCH + k2] = SA.y;
    sre[rB * PITCH + k2] = SB.x; sim[rB * PITCH + k2] = SB.y;

    // Row 32 post-pass (wave 0 only): u = -1, v = e^{2pi i/128} * el.
    if (w == 0) {
        v2f xC[16];
        #pragma unroll
        for (int c = 0; c < 16; ++c) {
            float2 q = Xt[c * 4096 + 32 * 64]; xC[c] = (v2f){q.x, q.y};
        }
        v2f TC[9];
        #pragma unroll
        for (int q = 0; q < 9; ++q) TC[q] = (v2f){0,0};
        #pragma unroll
        for (int c = 0; c < 16; ++c) {
            const float* wc = wo + c * 9;
            #pragma unroll
            for (int q = 0; q < 9; ++q) TC[q] += xC[c] * wc[q];
        }
        v2f vC = {C128 * elr - S128 * eli, C128 * eli + S128 * elr};
        v2f v2C = {vC.x * vC.x - vC.y * vC.y, 2.0f * vC.x * vC.y};
        v2f g0 = cmul_add(v2C, TC[2], cmul_add(vC, TC[1], TC[0]));
        v2f g1 = cmul_add(v2C, TC[5], cmul_add(vC, TC[4], TC[3]));
        v2f g2 = cmul_add(v2C, TC[8], cmul_add(vC, TC[7], TC[6]));
        v2f SC = g0 - g1 + g2;
        sre[32 * PITCH + k2] = SC.x; sim[32 * PITCH + k2] = SC.y;
    }
    __syncthreads();

    // Gather 4 rows per thread (direct or Hermitian mirror).
    float re[RPW], im[RPW];
    #pragma unroll
    for (int m = 0; m < RPW; ++m) {
        int k1 = w * RPW + m;
        if (k1 <= 32) {
            re[m] = sre[k1 * PITCH + k2];
            im[m] = sim[k1 * PITCH + k2];
        } else {
            int k1p = 64 - k1, k2p = 63 - k2;
            re[m] =  sre[k1p * PITCH + k2p];
            im[m] = -sim[k1p * PITCH + k2p];
        }
    }
    __syncthreads();   // gather done before tail overwrites sre/sim

    // Phase 1: inverse FFT over k2 (lanes hold k2 = brev6(l) -> DIT).
    fft64_dit_t<RPW>(re, im, lane, Ti);
    // Mid twiddle: * e^{+2pi i n2 k1 / 4096}, n2 = lane (independent sincos).
    #pragma unroll
    for (int m = 0; m < RPW; ++m) {
        int k1 = w * RPW + m;
        float cr, ci;
        __sincosf((TWO_PI / 4096.0f) * (float)(lane * k1), &ci, &cr);
        float rv = re[m] * cr - im[m] * ci;
        im[m]    = re[m] * ci + im[m] * cr;
        re[m]    = rv;
    }
    // Transpose through LDS: write [k1][n2].
    #pragma unroll
    for (int m = 0; m < RPW; ++m) {
        int k1 = w * RPW + m;
        sre[k1 * PITCH + lane] = re[m];
        sim[k1 * PITCH + lane] = im[m];
    }
    __syncthreads();
    // Phase 2: inverse FFT over k1 (lane = k1), columns n2 = w*4 + m.
    #pragma unroll
    for (int m = 0; m < RPW; ++m) {
        int n2 = w * RPW + m;
        re[m] = sre[lane * PITCH + n2];
        im[m] = sim[lane * PITCH + n2];
    }
    fft64_dif_t<RPW>(re, im, lane, Ti);
    __syncthreads();   // phase-2 reads done before y overwrite
    // Lane l holds y[n1 = brev6(l)][n2]; unscramble via LDS for coalesced store.
    const int n1 = brev6(lane);
    #pragma unroll
    for (int m = 0; m < RPW; ++m) {
        int n2 = w * RPW + m;
        sre[n1 * PITCH + n2] = re[m];
    }
    __syncthreads();
    const float bias = b[o];
    float* orow = out + (size_t)(t * 32 + o) * 62 * 62;
    for (int idx = tid; idx < 62 * 62; idx += NT) {
        int r = idx / 62, s = idx - r * 62;
        orow[idx] = sre[r * PITCH + s] * (1.0f / 4096.0f) + bias;
    }
}

extern "C" void kernel_launch(void* const* d_in, const int* in_sizes, int n_in,
                              void* d_out, int out_size, void* d_ws, size_t ws_size,
                              hipStream_t stream) {
    const float* x = (const float*)d_in[0];   // (8,16,62,62) f32
    const float* W = (const float*)d_in[1];   // (32,16,3,3)  f32
    const float* b = (const float*)d_in[2];   // (32,)        f32
    float* out = (float*)d_out;               // (8,32,62,62) f32
    float2* X = (float2*)d_ws;                // 128*4096 complex = 4 MB

    fwd_kernel<<<dim3(256), dim3(NT), 0, stream>>>(x, X);
    conv_kernel<<<dim3(256), dim3(NT), 0, stream>>>(X, W, b, out);
}

// Round 13
// 74.128 us; speedup vs baseline: 1.2975x; 1.0276x over previous
//
#include <hip/hip_runtime.h>
#include <math.h>

#define TWO_PI 6.28318530717958647692f
#define NT     1024          // 16 waves per block
#define RPW    4             // rows/cols per wave in FFT phases (64 / 16 waves)
#define PITCH  65            // LDS pitch (odd -> conflict-free both ways)
#define THRESH 10.0f
// e^{2pi i/128} (for k1 = 32 row: e^{2pi i 32/4096})
#define C128   0.998795456205172393f
#define S128   0.049067674327418015f

typedef float v2f __attribute__((ext_vector_type(2)));

__device__ __forceinline__ int brev6(int x) {
    return (int)(__brev((unsigned)x) >> 26);
}

// acc + a*b (complex)
__device__ __forceinline__ v2f cmul_add(v2f a, v2f b, v2f acc) {
    acc += (v2f){a.x, a.x} * b;
    acc += (v2f){a.y, a.y} * (v2f){-b.y, b.x};
    return acc;
}

// Per-lane stage twiddles for the 64-pt cross-lane FFT (6 stages).
struct Tw6 { v2f t[6]; };

__device__ __forceinline__ Tw6 make_tw6(int lane, float sign) {
    Tw6 T;
    #pragma unroll
    for (int s = 0; s < 6; ++s) {
        int h = 1 << s;
        int j = lane & (h - 1);
        float ang = sign * (TWO_PI / 64.0f) * (float)(j * (32 >> s));
        float c, si;
        __sincosf(ang, &si, &c);
        T.t[s] = (v2f){c, si};
    }
    return T;
}

// Cross-lane 64-pt DIF FFT, precomputed twiddles. Natural-order input across
// lanes; output: lane l holds coefficient brev6(l).
template<int R>
__device__ __forceinline__ void fft64_dif_t(float (&re)[R], float (&im)[R],
                                            int lane, const Tw6& T) {
    #pragma unroll
    for (int s = 5; s >= 0; --s) {
        const int h = 1 << s;
        float wr = T.t[s].x, wi = T.t[s].y;
        bool upper = (lane & h) != 0;
        float cwr = upper ? wr : 1.0f;
        float cwi = upper ? wi : 0.0f;
        float sgn = upper ? -1.0f : 1.0f;
        #pragma unroll
        for (int m = 0; m < R; ++m) {
            float orr = __shfl_xor(re[m], h, 64);
            float oii = __shfl_xor(im[m], h, 64);
            float ar = fmaf(sgn, re[m], orr);
            float ai = fmaf(sgn, im[m], oii);
            re[m] = ar * cwr - ai * cwi;
            im[m] = ar * cwi + ai * cwr;
        }
    }
}

// Cross-lane 64-pt DIT FFT, precomputed twiddles. Bit-reversed input across
// lanes; natural-order output.
template<int R>
__device__ __forceinline__ void fft64_dit_t(float (&re)[R], float (&im)[R],
                                            int lane, const Tw6& T) {
    #pragma unroll
    for (int s = 0; s < 6; ++s) {
        const int h = 1 << s;
        float wr = T.t[s].x, wi = T.t[s].y;
        bool upper = (lane & h) != 0;
        float cwr = upper ? wr : 1.0f;
        float cwi = upper ? wi : 0.0f;
        float sgn = upper ? -1.0f : 1.0f;
        #pragma unroll
        for (int m = 0; m < R; ++m) {
            float tr = re[m] * cwr - im[m] * cwi;
            float ti = re[m] * cwi + im[m] * cwr;
            float orr = __shfl_xor(tr, h, 64);
            float oii = __shfl_xor(ti, h, 64);
            re[m] = fmaf(sgn, tr, orr);
            im[m] = fmaf(sgn, ti, oii);
        }
    }
}

// S = sum_q T[q] * u^i v^j  (q = 3i + j), double Horner.
__device__ __forceinline__ v2f tap_combine(const v2f (&T)[9], v2f u, v2f v,
                                           v2f v2) {
    v2f g0 = cmul_add(v2, T[2], cmul_add(v, T[1], T[0]));
    v2f g1 = cmul_add(v2, T[5], cmul_add(v, T[4], T[3]));
    v2f g2 = cmul_add(v2, T[8], cmul_add(v, T[7], T[6]));
    return cmul_add(u, cmul_add(u, g2, g1), g0);
}

// fwd: 256 blocks. Block b: t = b&7 (XCD-pin), r = b>>3, c = r&15, h = r>>4.
// Both h-blocks of a task redo phase A; phase B's Hermitian rows k1<=32 are
// split: h=0 -> rows 0..15, h=1 -> 16..31 + 32.
// Store X[task][k1][l] = spectrum[k1 + 64*brev6(l)].
__global__ __launch_bounds__(NT) void fwd_kernel(const float* __restrict__ x,
                                                 float2* __restrict__ X) {
    __shared__ float sre[64 * PITCH];
    __shared__ float sim[64 * PITCH];
    const int bId  = blockIdx.x;
    const int t    = bId & 7;
    const int rr_  = bId >> 3;
    const int c    = rr_ & 15;
    const int h    = rr_ >> 4;
    const int task = t * 16 + c;
    const int tid  = threadIdx.x;
    const int lane = tid & 63;
    const int w    = tid >> 6;          // 0..15
    const float* xr = x + (size_t)task * 62 * 62;

    for (int idx = tid; idx < 4096; idx += NT) {
        int r = idx >> 6, s = idx & 63;
        float v = 0.0f;
        if (r >= 1 && r <= 62 && s >= 1 && s <= 62)
            v = xr[(r - 1) * 62 + (s - 1)];
        sre[r * PITCH + s] = v;
    }
    __syncthreads();

    const Tw6 Tf = make_tw6(lane, -1.0f);

    // Phase A (redundant in both h-blocks): FFT over n1, columns n2 = w*4+m.
    float re[RPW], im[RPW];
    #pragma unroll
    for (int m = 0; m < RPW; ++m) {
        re[m] = sre[lane * PITCH + (w * RPW + m)];
        im[m] = 0.0f;
    }
    fft64_dif_t<RPW>(re, im, lane, Tf);
    const int k1 = brev6(lane);
    // Mid twiddle: * e^{-2pi i k1 n2 / 4096}
    #pragma unroll
    for (int m = 0; m < RPW; ++m) {
        int n2 = w * RPW + m;
        float cr, ci;
        __sincosf(-(TWO_PI / 4096.0f) * (float)(k1 * n2), &ci, &cr);
        float rv = re[m] * cr - im[m] * ci;
        im[m]    = re[m] * ci + im[m] * cr;
        re[m]    = rv;
    }
    __syncthreads();                 // all phase-A reads done before overwrite
    #pragma unroll
    for (int m = 0; m < RPW; ++m) {
        int n2 = w * RPW + m;
        sre[k1 * PITCH + n2] = re[m];
        sim[k1 * PITCH + n2] = im[m];
    }
    __syncthreads();

    // Phase B: 1 row per wave (+ row 32 slot, stored by h=1 wave 0 only).
    float rb[2], ib[2];
    const int row0 = 16 * h + w;
    rb[0] = sre[row0 * PITCH + lane];
    ib[0] = sim[row0 * PITCH + lane];
    rb[1] = sre[32 * PITCH + lane];
    ib[1] = sim[32 * PITCH + lane];
    fft64_dif_t<2>(rb, ib, lane, Tf);
    float2* Xrow = X + (size_t)task * 4096;
    {
        float rv = rb[0], iv = ib[0];
        if (fabsf(rv) < THRESH) { rv = 0.0f; iv = 0.0f; }
        Xrow[row0 * 64 + lane] = make_float2(rv, iv);
    }
    if (h == 1 && w == 0) {
        float rv = rb[1], iv = ib[1];
        if (fabsf(rv) < THRESH) { rv = 0.0f; iv = 0.0f; }
        Xrow[32 * 64 + lane] = make_float2(rv, iv);
    }
}

// conv: block b: t = b&7 (XCD-pinned with fwd's X[t] producers), o = b>>3.
// Hermitian tap accumulation (rows 2w, 2w+1, +32 on wave 0), register-resident
// phase-1 DIT on ONLY those rows; mirror rows 33..63 are PURE CONJUGATES:
// Z'[64-k1][n2] = conj(Z'[k1][n2])  (midtwiddle cancels the e^{-2pi i n2/64}
// from the Hermitian fold -- verified derivation). Phase-2 DIF; crop + bias.
__global__ __launch_bounds__(NT, 3) void conv_kernel(const float2* __restrict__ X,
                                                     const float* __restrict__ W,
                                                     const float* __restrict__ b,
                                                     float* __restrict__ out) {
    __shared__ float sre[64 * PITCH];
    __shared__ float sim[64 * PITCH];
    const int t    = blockIdx.x & 7;
    const int o    = blockIdx.x >> 3;
    const int tid  = threadIdx.x;
    const int lane = tid & 63;
    const int w    = tid >> 6;          // 0..15

    const int k2 = brev6(lane);
    float elr, eli;          // e^{+2pi i k2/64}
    __sincosf((TWO_PI / 64.0f) * (float)k2, &eli, &elr);

    const Tw6 Ti = make_tw6(lane, +1.0f);

    // Slot twiddles: A: k1=2w, B: k1=2w+1.
    const int rA = 2 * w, rB = 2 * w + 1;
    float uAr, uAi, vAr, vAi, uBr, uBi, vBr, vBi;
    __sincosf((TWO_PI / 64.0f) * (float)rA, &uAi, &uAr);
    __sincosf((TWO_PI / 4096.0f) * (float)rA, &vAi, &vAr);
    __sincosf((TWO_PI / 64.0f) * (float)rB, &uBi, &uBr);
    __sincosf((TWO_PI / 4096.0f) * (float)rB, &vBi, &vBr);
    v2f uA = {uAr, uAi};
    v2f vA = {vAr * elr - vAi * eli, vAr * eli + vAi * elr};
    v2f v2A = {vA.x * vA.x - vA.y * vA.y, 2.0f * vA.x * vA.y};
    v2f uB = {uBr, uBi};
    v2f vB = {vBr * elr - vBi * eli, vBr * eli + vBi * elr};
    v2f v2B = {vB.x * vB.x - vB.y * vB.y, 2.0f * vB.x * vB.y};

    const float2* Xt = X + (size_t)t * 16 * 4096 + lane;
    const float*  wo = W + o * 144;     // block-uniform -> scalar loads

    // Issue ALL 32 loads upfront (16 channels x 2 slots).
    v2f xA[16], xB[16];
    #pragma unroll
    for (int c = 0; c < 16; ++c) {
        { float2 q = Xt[c * 4096 + rA * 64]; xA[c] = (v2f){q.x, q.y}; }
        { float2 q = Xt[c * 4096 + rB * 64]; xB[c] = (v2f){q.x, q.y}; }
    }
    // Tap accumulation: T[q] = sum_c W[c,q] * X[c]  (pure FMA, 9 accumulators)
    v2f TA[9], TB[9];
    #pragma unroll
    for (int q = 0; q < 9; ++q) { TA[q] = (v2f){0,0}; TB[q] = (v2f){0,0}; }
    #pragma unroll
    for (int c = 0; c < 16; ++c) {
        const float* wc = wo + c * 9;
        #pragma unroll
        for (int q = 0; q < 9; ++q) {
            float wq = wc[q];
            TA[q] += xA[c] * wq;
            TB[q] += xB[c] * wq;
        }
    }
    v2f SA = tap_combine(TA, uA, vA, v2A);
    v2f SB = tap_combine(TB, uB, vB, v2B);

    // Phase 1 (register-resident): DIT over k2 for own rows only.
    float pr[2] = {SA.x, SB.x};
    float pi[2] = {SA.y, SB.y};
    fft64_dit_t<2>(pr, pi, lane, Ti);   // lane -> n2 (natural order)

    // Mid twiddle per row: * e^{+2pi i n2 k1 / 4096}, n2 = lane.
    {
        float cr, ci;
        __sincosf((TWO_PI / 4096.0f) * (float)(lane * rA), &ci, &cr);
        float rv = pr[0] * cr - pi[0] * ci;
        pi[0]    = pr[0] * ci + pi[0] * cr;
        pr[0]    = rv;
        __sincosf((TWO_PI / 4096.0f) * (float)(lane * rB), &ci, &cr);
        rv    = pr[1] * cr - pi[1] * ci;
        pi[1] = pr[1] * ci + pi[1] * cr;
        pr[1] = rv;
    }

    // Own rows.
    sre[rA * PITCH + lane] = pr[0]; sim[rA * PITCH + lane] = pi[0];
    sre[rB * PITCH + lane] = pr[1]; sim[rB * PITCH + lane] = pi[1];
    // Mirror rows: Z'[64-k1][n2] = conj(Z'[k1][n2]).
    {   // mirror of rB = 63 - 2w (valid for all w)
        sre[(64 - rB) * PITCH + lane] =  pr[1];
        sim[(64 - rB) * PITCH + lane] = -pi[1];
    }
    if (w > 0) {   // mirror of rA = 64 - 2w
        sre[(64 - rA) * PITCH + lane] =  pr[0];
        sim[(64 - rA) * PITCH + lane] = -pi[0];
    }
    // Row 32 (wave 0): compute, DIT, midtwiddle e^{2pi i lane/128}, store.
    if (w == 0) {
        v2f xC[16];
        #pragma unroll
        for (int c = 0; c < 16; ++c) {
            float2 q = Xt[c * 4096 + 32 * 64]; xC[c] = (v2f){q.x, q.y};
        }
        v2f TC[9];
        #pragma unroll
        for (int q = 0; q < 9; ++q) TC[q] = (v2f){0,0};
        #pragma unroll
        for (int c = 0; c < 16; ++c) {
            const float* wc = wo + c * 9;
            #pragma unroll
            for (int q = 0; q < 9; ++q) TC[q] += xC[c] * wc[q];
        }
        v2f vC = {C128 * elr - S128 * eli, C128 * eli + S128 * elr};
        v2f v2C = {vC.x * vC.x - vC.y * vC.y, 2.0f * vC.x * vC.y};
        v2f g0 = cmul_add(v2C, TC[2], cmul_add(vC, TC[1], TC[0]));
        v2f g1 = cmul_add(v2C, TC[5], cmul_add(vC, TC[4], TC[3]));
        v2f g2 = cmul_add(v2C, TC[8], cmul_add(vC, TC[7], TC[6]));
        v2f SC = g0 - g1 + g2;           // u = -1 at k1 = 32
        float cr_[1] = {SC.x}, ci_[1] = {SC.y};
        fft64_dit_t<1>(cr_, ci_, lane, Ti);
        float cr, ci;                    // e^{+2pi i lane*32/4096}
        __sincosf((TWO_PI / 128.0f) * (float)lane, &ci, &cr);
        float rv = cr_[0] * cr - ci_[0] * ci;
        float iv = cr_[0] * ci + ci_[0] * cr;
        sre[32 * PITCH + lane] = rv;
        sim[32 * PITCH + lane] = iv;
    }
    __syncthreads();

    // Phase 2: inverse FFT over k1 (lane = k1), columns n2 = w*4 + m.
    float re[RPW], im[RPW];
    #pragma unroll
    for (int m = 0; m < RPW; ++m) {
        int n2 = w * RPW + m;
        re[m] = sre[lane * PITCH + n2];
        im[m] = sim[lane * PITCH + n2];
    }
    fft64_dif_t<RPW>(re, im, lane, Ti);
    __syncthreads();   // phase-2 reads done before y overwrite
    // Lane l holds y[n1 = brev6(l)][n2]; unscramble via LDS for coalesced store.
    const int n1 = brev6(lane);
    #pragma unroll
    for (int m = 0; m < RPW; ++m) {
        int n2 = w * RPW + m;
        sre[n1 * PITCH + n2] = re[m];
    }
    __syncthreads();
    const float bias = b[o];
    float* orow = out + (size_t)(t * 32 + o) * 62 * 62;
    for (int idx = tid; idx < 62 * 62; idx += NT) {
        int r = idx / 62, s = idx - r * 62;
        orow[idx] = sre[r * PITCH + s] * (1.0f / 4096.0f) + bias;
    }
}

extern "C" void kernel_launch(void* const* d_in, const int* in_sizes, int n_in,
                              void* d_out, int out_size, void* d_ws, size_t ws_size,
                              hipStream_t stream) {
    const float* x = (const float*)d_in[0];   // (8,16,62,62) f32
    const float* W = (const float*)d_in[1];   // (32,16,3,3)  f32
    const float* b = (const float*)d_in[2];   // (32,)        f32
    float* out = (float*)d_out;               // (8,32,62,62) f32
    float2* X = (float2*)d_ws;                // 128*4096 complex = 4 MB

    fwd_kernel<<<dim3(256), dim3(NT), 0, stream>>>(x, X);
    conv_kernel<<<dim3(256), dim3(NT), 0, stream>>>(X, W, b, out);
}

// Round 14
// 73.087 us; speedup vs baseline: 1.3159x; 1.0142x over previous
//
#include <hip/hip_runtime.h>
#include <math.h>

#define TWO_PI 6.28318530717958647692f
#define NT     1024          // 16 waves per block
#define RPW    4             // cols per wave in FFT phases (64 / 16 waves)
#define PITCH  65            // LDS pitch (odd -> conflict-free both ways)
#define THRESH 10.0f
// e^{2pi i/128} (for k1 = 32 row: e^{2pi i 32/4096})
#define C128   0.998795456205172393f
#define S128   0.049067674327418015f

typedef float v2f __attribute__((ext_vector_type(2)));

__device__ __forceinline__ int brev6(int x) {
    return (int)(__brev((unsigned)x) >> 26);
}

// acc + a*b (complex)
__device__ __forceinline__ v2f cmul_add(v2f a, v2f b, v2f acc) {
    acc += (v2f){a.x, a.x} * b;
    acc += (v2f){a.y, a.y} * (v2f){-b.y, b.x};
    return acc;
}

// Per-lane stage twiddles for the 64-pt cross-lane FFT (6 stages).
struct Tw6 { v2f t[6]; };

__device__ __forceinline__ Tw6 make_tw6(int lane, float sign) {
    Tw6 T;
    #pragma unroll
    for (int s = 0; s < 6; ++s) {
        int h = 1 << s;
        int j = lane & (h - 1);
        float ang = sign * (TWO_PI / 64.0f) * (float)(j * (32 >> s));
        float c, si;
        __sincosf(ang, &si, &c);
        T.t[s] = (v2f){c, si};
    }
    return T;
}

// Cross-lane 64-pt DIF FFT, precomputed twiddles. Natural-order input across
// lanes; output: lane l holds coefficient brev6(l).
template<int R>
__device__ __forceinline__ void fft64_dif_t(float (&re)[R], float (&im)[R],
                                            int lane, const Tw6& T) {
    #pragma unroll
    for (int s = 5; s >= 0; --s) {
        const int h = 1 << s;
        float wr = T.t[s].x, wi = T.t[s].y;
        bool upper = (lane & h) != 0;
        float cwr = upper ? wr : 1.0f;
        float cwi = upper ? wi : 0.0f;
        float sgn = upper ? -1.0f : 1.0f;
        #pragma unroll
        for (int m = 0; m < R; ++m) {
            float orr = __shfl_xor(re[m], h, 64);
            float oii = __shfl_xor(im[m], h, 64);
            float ar = fmaf(sgn, re[m], orr);
            float ai = fmaf(sgn, im[m], oii);
            re[m] = ar * cwr - ai * cwi;
            im[m] = ar * cwi + ai * cwr;
        }
    }
}

// Cross-lane 64-pt DIT FFT, precomputed twiddles. Bit-reversed input across
// lanes; natural-order output.
template<int R>
__device__ __forceinline__ void fft64_dit_t(float (&re)[R], float (&im)[R],
                                            int lane, const Tw6& T) {
    #pragma unroll
    for (int s = 0; s < 6; ++s) {
        const int h = 1 << s;
        float wr = T.t[s].x, wi = T.t[s].y;
        bool upper = (lane & h) != 0;
        float cwr = upper ? wr : 1.0f;
        float cwi = upper ? wi : 0.0f;
        float sgn = upper ? -1.0f : 1.0f;
        #pragma unroll
        for (int m = 0; m < R; ++m) {
            float tr = re[m] * cwr - im[m] * cwi;
            float ti = re[m] * cwi + im[m] * cwr;
            float orr = __shfl_xor(tr, h, 64);
            float oii = __shfl_xor(ti, h, 64);
            re[m] = fmaf(sgn, tr, orr);
            im[m] = fmaf(sgn, ti, oii);
        }
    }
}

// S = sum_q T[q] * u^i v^j  (q = 3i + j), double Horner.
__device__ __forceinline__ v2f tap_combine(const v2f (&T)[9], v2f u, v2f v,
                                           v2f v2) {
    v2f g0 = cmul_add(v2, T[2], cmul_add(v, T[1], T[0]));
    v2f g1 = cmul_add(v2, T[5], cmul_add(v, T[4], T[3]));
    v2f g2 = cmul_add(v2, T[8], cmul_add(v, T[7], T[6]));
    return cmul_add(u, cmul_add(u, g2, g1), g0);
}

// fwd: 256 blocks. Block b: t = b&7 (XCD-pin), r = b>>3, c = r&15, h = r>>4.
// Phase A packs REAL column pairs into one complex FFT (half the FFTs),
// unpacks via mirror-lane shuffle. Phase B rows k1<=32 split: h=0 -> 0..15,
// h=1 -> 16..31 + 32. Store X[task][k1][l] = spectrum[k1 + 64*brev6(l)].
__global__ __launch_bounds__(NT) void fwd_kernel(const float* __restrict__ x,
                                                 float2* __restrict__ X) {
    __shared__ float sre[64 * PITCH];
    __shared__ float sim[64 * PITCH];
    const int bId  = blockIdx.x;
    const int t    = bId & 7;
    const int rr_  = bId >> 3;
    const int c    = rr_ & 15;
    const int h    = rr_ >> 4;
    const int task = t * 16 + c;
    const int tid  = threadIdx.x;
    const int lane = tid & 63;
    const int w    = tid >> 6;          // 0..15
    const float* xr = x + (size_t)task * 62 * 62;

    for (int idx = tid; idx < 4096; idx += NT) {
        int r = idx >> 6, s = idx & 63;
        float v = 0.0f;
        if (r >= 1 && r <= 62 && s >= 1 && s <= 62)
            v = xr[(r - 1) * 62 + (s - 1)];
        sre[r * PITCH + s] = v;
    }
    __syncthreads();

    const Tw6 Tf = make_tw6(lane, -1.0f);

    // Phase A (packed): z[p] = col(4w+2p) + i*col(4w+2p+1), lane = n1.
    float zr[2], zi[2];
    #pragma unroll
    for (int p = 0; p < 2; ++p) {
        zr[p] = sre[lane * PITCH + (w * 4 + 2 * p)];
        zi[p] = sre[lane * PITCH + (w * 4 + 2 * p + 1)];
    }
    __syncthreads();                 // input reads done before row overwrite
    fft64_dif_t<2>(zr, zi, lane, Tf);
    const int k1 = brev6(lane);
    const int ml = brev6((64 - k1) & 63);   // lane holding Z[-k1]
    #pragma unroll
    for (int p = 0; p < 2; ++p) {
        float mr = __shfl(zr[p], ml, 64);
        float mi = __shfl(zi[p], ml, 64);
        // FA = (Z + conj(Zm))/2 ; FB = (Z - conj(Zm))/(2i)
        float far = 0.5f * (zr[p] + mr), fai = 0.5f * (zi[p] - mi);
        float fbr = 0.5f * (zi[p] + mi), fbi = 0.5f * (mr - zr[p]);
        int n2a = w * 4 + 2 * p, n2b = n2a + 1;
        float cr, ci;                // midtwiddle e^{-2pi i k1 n2 / 4096}
        __sincosf(-(TWO_PI / 4096.0f) * (float)(k1 * n2a), &ci, &cr);
        sre[k1 * PITCH + n2a] = far * cr - fai * ci;
        sim[k1 * PITCH + n2a] = far * ci + fai * cr;
        __sincosf(-(TWO_PI / 4096.0f) * (float)(k1 * n2b), &ci, &cr);
        sre[k1 * PITCH + n2b] = fbr * cr - fbi * ci;
        sim[k1 * PITCH + n2b] = fbr * ci + fbi * cr;
    }
    __syncthreads();

    // Phase B: 1 row per wave (+ row 32 slot, stored by h=1 wave 0 only).
    float rb[2], ib[2];
    const int row0 = 16 * h + w;
    rb[0] = sre[row0 * PITCH + lane];
    ib[0] = sim[row0 * PITCH + lane];
    rb[1] = sre[32 * PITCH + lane];
    ib[1] = sim[32 * PITCH + lane];
    fft64_dif_t<2>(rb, ib, lane, Tf);
    float2* Xrow = X + (size_t)task * 4096;
    {
        float rv = rb[0], iv = ib[0];
        if (fabsf(rv) < THRESH) { rv = 0.0f; iv = 0.0f; }
        Xrow[row0 * 64 + lane] = make_float2(rv, iv);
    }
    if (h == 1 && w == 0) {
        float rv = rb[1], iv = ib[1];
        if (fabsf(rv) < THRESH) { rv = 0.0f; iv = 0.0f; }
        Xrow[32 * 64 + lane] = make_float2(rv, iv);
    }
}

// conv: block b: t = b&7, o = b>>3. Hermitian tap accumulation (rows 2w,
// 2w+1, +32 on wave 0), register-resident phase-1 DIT; only rows 0..32 kept
// in LDS. Phase 2 packs Hermitian column pairs into one complex iFFT
// (real outputs in re/im); crop + bias.
__global__ __launch_bounds__(NT, 3) void conv_kernel(const float2* __restrict__ X,
                                                     const float* __restrict__ W,
                                                     const float* __restrict__ b,
                                                     float* __restrict__ out) {
    __shared__ float sre[64 * PITCH];
    __shared__ float sim[64 * PITCH];
    const int t    = blockIdx.x & 7;
    const int o    = blockIdx.x >> 3;
    const int tid  = threadIdx.x;
    const int lane = tid & 63;
    const int w    = tid >> 6;          // 0..15

    const int k2 = brev6(lane);
    float elr, eli;          // e^{+2pi i k2/64}
    __sincosf((TWO_PI / 64.0f) * (float)k2, &eli, &elr);

    const Tw6 Ti = make_tw6(lane, +1.0f);

    // Slot twiddles: A: k1=2w, B: k1=2w+1.
    const int rA = 2 * w, rB = 2 * w + 1;
    float uAr, uAi, vAr, vAi, uBr, uBi, vBr, vBi;
    __sincosf((TWO_PI / 64.0f) * (float)rA, &uAi, &uAr);
    __sincosf((TWO_PI / 4096.0f) * (float)rA, &vAi, &vAr);
    __sincosf((TWO_PI / 64.0f) * (float)rB, &uBi, &uBr);
    __sincosf((TWO_PI / 4096.0f) * (float)rB, &vBi, &vBr);
    v2f uA = {uAr, uAi};
    v2f vA = {vAr * elr - vAi * eli, vAr * eli + vAi * elr};
    v2f v2A = {vA.x * vA.x - vA.y * vA.y, 2.0f * vA.x * vA.y};
    v2f uB = {uBr, uBi};
    v2f vB = {vBr * elr - vBi * eli, vBr * eli + vBi * elr};
    v2f v2B = {vB.x * vB.x - vB.y * vB.y, 2.0f * vB.x * vB.y};

    const float2* Xt = X + (size_t)t * 16 * 4096 + lane;
    const float*  wo = W + o * 144;     // block-uniform -> scalar loads

    // Issue ALL 32 loads upfront (16 channels x 2 slots).
    v2f xA[16], xB[16];
    #pragma unroll
    for (int c = 0; c < 16; ++c) {
        { float2 q = Xt[c * 4096 + rA * 64]; xA[c] = (v2f){q.x, q.y}; }
        { float2 q = Xt[c * 4096 + rB * 64]; xB[c] = (v2f){q.x, q.y}; }
    }
    // Tap accumulation: T[q] = sum_c W[c,q] * X[c]  (pure FMA, 9 accumulators)
    v2f TA[9], TB[9];
    #pragma unroll
    for (int q = 0; q < 9; ++q) { TA[q] = (v2f){0,0}; TB[q] = (v2f){0,0}; }
    #pragma unroll
    for (int c = 0; c < 16; ++c) {
        const float* wc = wo + c * 9;
        #pragma unroll
        for (int q = 0; q < 9; ++q) {
            float wq = wc[q];
            TA[q] += xA[c] * wq;
            TB[q] += xB[c] * wq;
        }
    }
    v2f SA = tap_combine(TA, uA, vA, v2A);
    v2f SB = tap_combine(TB, uB, vB, v2B);

    // Phase 1 (register-resident): DIT over k2 for own rows only.
    float pr[2] = {SA.x, SB.x};
    float pi[2] = {SA.y, SB.y};
    fft64_dit_t<2>(pr, pi, lane, Ti);   // lane -> n2 (natural order)

    // Mid twiddle per row: * e^{+2pi i n2 k1 / 4096}, n2 = lane.
    {
        float cr, ci;
        __sincosf((TWO_PI / 4096.0f) * (float)(lane * rA), &ci, &cr);
        float rv = pr[0] * cr - pi[0] * ci;
        pi[0]    = pr[0] * ci + pi[0] * cr;
        pr[0]    = rv;
        __sincosf((TWO_PI / 4096.0f) * (float)(lane * rB), &ci, &cr);
        rv    = pr[1] * cr - pi[1] * ci;
        pi[1] = pr[1] * ci + pi[1] * cr;
        pr[1] = rv;
    }

    // Publish own rows (0..32 only; mirrors handled by conj-read in phase 2).
    sre[rA * PITCH + lane] = pr[0]; sim[rA * PITCH + lane] = pi[0];
    sre[rB * PITCH + lane] = pr[1]; sim[rB * PITCH + lane] = pi[1];
    // Row 32 (wave 0): compute, DIT, midtwiddle e^{2pi i lane/128}, store.
    if (w == 0) {
        v2f xC[16];
        #pragma unroll
        for (int c = 0; c < 16; ++c) {
            float2 q = Xt[c * 4096 + 32 * 64]; xC[c] = (v2f){q.x, q.y};
        }
        v2f TC[9];
        #pragma unroll
        for (int q = 0; q < 9; ++q) TC[q] = (v2f){0,0};
        #pragma unroll
        for (int c = 0; c < 16; ++c) {
            const float* wc = wo + c * 9;
            #pragma unroll
            for (int q = 0; q < 9; ++q) TC[q] += xC[c] * wc[q];
        }
        v2f vC = {C128 * elr - S128 * eli, C128 * eli + S128 * elr};
        v2f v2C = {vC.x * vC.x - vC.y * vC.y, 2.0f * vC.x * vC.y};
        v2f g0 = cmul_add(v2C, TC[2], cmul_add(vC, TC[1], TC[0]));
        v2f g1 = cmul_add(v2C, TC[5], cmul_add(vC, TC[4], TC[3]));
        v2f g2 = cmul_add(v2C, TC[8], cmul_add(vC, TC[7], TC[6]));
        v2f SC = g0 - g1 + g2;           // u = -1 at k1 = 32
        float cr_[1] = {SC.x}, ci_[1] = {SC.y};
        fft64_dit_t<1>(cr_, ci_, lane, Ti);
        float cr, ci;                    // e^{+2pi i lane*32/4096}
        __sincosf((TWO_PI / 128.0f) * (float)lane, &ci, &cr);
        float rv = cr_[0] * cr - ci_[0] * ci;
        float iv = cr_[0] * ci + ci_[0] * cr;
        sre[32 * PITCH + lane] = rv;
        sim[32 * PITCH + lane] = iv;
    }
    __syncthreads();

    // Phase 2 (packed): Hermitian columns -> real iFFTs, two per complex FFT.
    // P[p] = Z'[:, n2a] + i * Z'[:, n2b]; lane = k1 (rows >32 read as conj).
    const int row  = (lane <= 32) ? lane : 64 - lane;
    const float sg = (lane <= 32) ? 1.0f : -1.0f;
    float yr[2], yi[2];
    #pragma unroll
    for (int p = 0; p < 2; ++p) {
        int n2a = w * 4 + 2 * p, n2b = n2a + 1;
        float ar = sre[row * PITCH + n2a], ai = sg * sim[row * PITCH + n2a];
        float br = sre[row * PITCH + n2b], bi = sg * sim[row * PITCH + n2b];
        yr[p] = ar - bi;
        yi[p] = ai + br;
    }
    fft64_dif_t<2>(yr, yi, lane, Ti);
    __syncthreads();   // phase-2 reads done before y overwrite
    // Lane l holds y[n1 = brev6(l)] for both columns (re/im are the two cols).
    const int n1 = brev6(lane);
    #pragma unroll
    for (int p = 0; p < 2; ++p) {
        int n2a = w * 4 + 2 * p, n2b = n2a + 1;
        sre[n1 * PITCH + n2a] = yr[p];
        sre[n1 * PITCH + n2b] = yi[p];
    }
    __syncthreads();
    const float bias = b[o];
    float* orow = out + (size_t)(t * 32 + o) * 62 * 62;
    for (int idx = tid; idx < 62 * 62; idx += NT) {
        int r = idx / 62, s = idx - r * 62;
        orow[idx] = sre[r * PITCH + s] * (1.0f / 4096.0f) + bias;
    }
}

extern "C" void kernel_launch(void* const* d_in, const int* in_sizes, int n_in,
                              void* d_out, int out_size, void* d_ws, size_t ws_size,
                              hipStream_t stream) {
    const float* x = (const float*)d_in[0];   // (8,16,62,62) f32
    const float* W = (const float*)d_in[1];   // (32,16,3,3)  f32
    const float* b = (const float*)d_in[2];   // (32,)        f32
    float* out = (float*)d_out;               // (8,32,62,62) f32
    float2* X = (float2*)d_ws;                // 128*4096 complex = 4 MB

    fwd_kernel<<<dim3(256), dim3(NT), 0, stream>>>(x, X);
    conv_kernel<<<dim3(256), dim3(NT), 0, stream>>>(X, W, b, out);
}